// Round 6
// baseline (679.703 us; speedup 1.0000x reference)
//
#include <hip/hip_runtime.h>
#include <math.h>

#define LRELU(y) ((y) > 0.f ? (y) : 0.01f * (y))
__device__ __constant__ float BNS = 0.99999500003749969f; // 1/sqrt(1+1e-5)

typedef unsigned short u16;
typedef __attribute__((ext_vector_type(8))) short bf16x8;
typedef __attribute__((ext_vector_type(4))) float f32x4;

__device__ inline u16 f2b(float f) {
  union { float f; unsigned u; } x; x.f = f;
  return (u16)((x.u + 0x7FFFu + ((x.u >> 16) & 1u)) >> 16);
}
__device__ inline float b2f(u16 b) {
  union { unsigned u; float f; } x; x.u = ((unsigned)b) << 16;
  return x.f;
}
__device__ inline float4 b2f4(ushort4 u) {
  float4 r;
  r.x = b2f(u.x); r.y = b2f(u.y); r.z = b2f(u.z); r.w = b2f(u.w);
  return r;
}
__device__ inline float ldv(const float* p) { return *p; }
__device__ inline float ldv(const u16* p) { return b2f(*p); }

// fast tanh: 1 - 2/(e^{2|x|}+1), sign restored. exp-based, no libcall.
__device__ inline float ftanh(float x) {
  float e = __expf(2.0f * fabsf(x));
  float t = 1.0f - 2.0f / (e + 1.0f);
  return x < 0.f ? -t : t;
}

// Named-scalar FMA expansions (VGPR-only accumulators).
#define FM16(I0, I1, I2, I3, WV)                                        \
  a00 += (I0) * (WV).x; a01 += (I0) * (WV).y;                           \
  a02 += (I0) * (WV).z; a03 += (I0) * (WV).w;                           \
  a10 += (I1) * (WV).x; a11 += (I1) * (WV).y;                           \
  a12 += (I1) * (WV).z; a13 += (I1) * (WV).w;                           \
  a20 += (I2) * (WV).x; a21 += (I2) * (WV).y;                           \
  a22 += (I2) * (WV).z; a23 += (I2) * (WV).w;                           \
  a30 += (I3) * (WV).x; a31 += (I3) * (WV).y;                           \
  a32 += (I3) * (WV).z; a33 += (I3) * (WV).w;

#define FM12(I0, I1, I2, I3, WV)                                        \
  a0x += (I0) * (WV).x; a0y += (I0) * (WV).y; a0z += (I0) * (WV).z;     \
  a1x += (I1) * (WV).x; a1y += (I1) * (WV).y; a1z += (I1) * (WV).z;     \
  a2x += (I2) * (WV).x; a2y += (I2) * (WV).y; a2z += (I2) * (WV).z;     \
  a3x += (I3) * (WV).x; a3y += (I3) * (WV).y; a3z += (I3) * (WV).z;

// ---------------------------------------------------------------------------
// cast fp32 -> bf16
// ---------------------------------------------------------------------------
__global__ __launch_bounds__(256) void cast_kernel(
    const float* __restrict__ s, u16* __restrict__ d, int n4) {
  int i = blockIdx.x * 256 + threadIdx.x;
  if (i >= n4) return;
  float4 v = ((const float4*)s)[i];
  ushort4 o;
  o.x = f2b(v.x); o.y = f2b(v.y); o.z = f2b(v.z); o.w = f2b(v.w);
  ((ushort4*)d)[i] = o;
}

// fc1 weight: cast + permute columns k=oc*152+sp -> k'=sp*64+oc
__global__ __launch_bounds__(256) void wcast_fc1_kernel(
    const float* __restrict__ w, u16* __restrict__ wp) {
  int idx = blockIdx.x * 256 + threadIdx.x;
  if (idx >= 1024 * 9728) return;
  int n = idx / 9728, kp = idx % 9728;
  int sp = kp >> 6, oc = kp & 63;
  wp[idx] = f2b(w[(long)n * 9728 + oc * 152 + sp]);
}

// conv weight -> padded bf16 (64 x KP)
__global__ __launch_bounds__(256) void wpad_kernel(
    const float* __restrict__ w, u16* __restrict__ wp, int OC, int K, int KP) {
  int idx = blockIdx.x * 256 + threadIdx.x;
  if (idx >= 64 * KP) return;
  int row = idx / KP, col = idx % KP;
  wp[idx] = (row < OC && col < K) ? f2b(w[row * K + col]) : (u16)0;
}

// ---------------------------------------------------------------------------
// prep: x (128,3,300,25,2) -> dm (256,3,299,25) fp32, x0 (256,3,25) fp32
// ---------------------------------------------------------------------------
__global__ __launch_bounds__(256) void prep_kernel(
    const float* __restrict__ x, const float* __restrict__ g,
    const float* __restrict__ b, float* __restrict__ dm,
    float* __restrict__ x0) {
  int idx = blockIdx.x * 256 + threadIdx.x;
  if (idx >= 256 * 3 * 300 * 25) return;
  int v = idx % 25;
  int t = (idx / 25) % 300;
  int c = (idx / (25 * 300)) % 3;
  int nm = idx / (25 * 300 * 3);
  int n = nm >> 1, m = nm & 1;
  int ch = m * 75 + v * 3 + c;
  float s = g[ch] * BNS, bb = b[ch];
  long xi = (((long)(n * 3 + c) * 300 + t) * 25 + v) * 2 + m;
  float xm_t = x[xi] * s + bb;
  if (t == 0) x0[(nm * 3 + c) * 25 + v] = xm_t;
  if (t < 299) {
    float xm_t1 = x[xi + 50] * s + bb;
    dm[((nm * 3 + c) * 299 + t) * 25 + v] = xm_t1 - xm_t;
  }
}

// ---------------------------------------------------------------------------
// z flags: one wave per (nm,t)
// ---------------------------------------------------------------------------
__global__ __launch_bounds__(256) void zflag_kernel(
    const float* __restrict__ dm, unsigned char* __restrict__ z) {
  int gw = blockIdx.x * 4 + (threadIdx.x >> 6);
  if (gw >= 256 * 300) return;
  int lane = threadIdx.x & 63;
  int t = gw % 300, nm = gw / 300;
  bool nz = false;
  if (t < 299) {
    const float* base = dm + (long)nm * 3 * 299 * 25 + t * 25;
    if (lane < 75) {
      int c = lane / 25, v = lane % 25;
      nz = base[c * 299 * 25 + v] != 0.f;
    }
    int l2 = lane + 64;
    if (l2 < 75) {
      int c = l2 / 25, v = l2 % 25;
      nz = nz || (base[c * 299 * 25 + v] != 0.f);
    }
  }
  unsigned long long mask = __ballot(nz);
  if (lane == 0) z[nm * 300 + t] = (unsigned char)((t < 299) && (mask == 0ull));
}

// ---------------------------------------------------------------------------
// conv1 (VALU tiled, fp32 in, bf16 out)
// ---------------------------------------------------------------------------
template <typename TI, int IC, int OC, int OCB, int ACC, int H, int W, int OH,
          int OW, int TOH, int NTILE>
__global__ __launch_bounds__(256) void conv_tiled_kernel(
    const TI* __restrict__ in, const float* __restrict__ w,
    const float* __restrict__ cb, const float* __restrict__ bg,
    const float* __restrict__ bnb, u16* __restrict__ out) {
  constexpr int IHT = 2 * TOH + 1;
  constexpr int RL = W + 2;
  __shared__ float in_s[IC * IHT * RL];
  __shared__ float w_s[9 * IC * OCB];
  int bx = blockIdx.x;
  int nm = blockIdx.y;
  int tile = bx % NTILE;
  int oc0 = (bx / NTILE) * OCB;
  int oh0 = tile * TOH;
  int ih0 = 2 * oh0 - 1;
  const TI* inb = in + (long)nm * IC * H * W;
  for (int e = threadIdx.x; e < IC * IHT * RL; e += 256) {
    int c = e % RL;
    int r = (e / RL) % IHT;
    int ic = e / (RL * IHT);
    int ih = ih0 + r, iw = c - 1;
    float v = 0.f;
    if (ih >= 0 && ih < H && iw >= 0 && iw < W) v = ldv(&inb[(ic * H + ih) * W + iw]);
    in_s[e] = v;
  }
  for (int e = threadIdx.x; e < 9 * IC * OCB; e += 256) {
    int ocl = e % OCB;
    int ic = (e / OCB) % IC;
    int khw = e / (OCB * IC);
    int kh = khw / 3, kw = khw % 3;
    w_s[e] = w[(((oc0 + ocl) * IC + ic) * 3 + kh) * 3 + kw];
  }
  __syncthreads();
  constexpr int NPOS = TOH * OW;
  constexpr int NWI = NPOS * (OCB / ACC);
  for (int wi = threadIdx.x; wi < NWI; wi += 256) {
    int pos = wi % NPOS;
    int jb = (wi / NPOS) * ACC;
    int ow = pos % OW;
    int oh_l = pos / OW;
    int oh = oh0 + oh_l;
    if (oh >= OH) continue;
    float acc[ACC];
#pragma unroll
    for (int j = 0; j < ACC; ++j) acc[j] = 0.f;
    for (int kh = 0; kh < 3; ++kh) {
      int r = 2 * oh_l + kh;
      for (int kw = 0; kw < 3; ++kw) {
        int cc = 2 * ow + kw;
        const float* ip = &in_s[r * RL + cc];
        const float* wp = &w_s[(kh * 3 + kw) * IC * OCB + jb];
        for (int ic = 0; ic < IC; ++ic) {
          float a = ip[ic * IHT * RL];
#pragma unroll
          for (int j = 0; j < ACC; ++j) acc[j] += a * wp[ic * OCB + j];
        }
      }
    }
#pragma unroll
    for (int j = 0; j < ACC; ++j) {
      int oc = oc0 + jb + j;
      float y = (acc[j] + cb[oc]) * (bg[oc] * BNS) + bnb[oc];
      out[((long)nm * OC + oc) * OH * OW + oh * OW + ow] = f2b(LRELU(y));
    }
  }
}

// ---------------------------------------------------------------------------
// im2col: build bf16 patch (m, KP), stride-2, pad 1, 3x3.
// ---------------------------------------------------------------------------
template <int IC, int H, int W, int OWW, int K, int KP, bool NHWC>
__global__ __launch_bounds__(256) void im2col_kernel(
    const u16* __restrict__ in, u16* __restrict__ patch, int m_off,
    int spatial, int n_threads) {
  int idx = blockIdx.x * 256 + threadIdx.x;
  if (idx >= n_threads) return;
  constexpr int KP8 = KP / 8;
  int m = idx / KP8;
  int k0 = (idx % KP8) * 8;
  int gm = m_off + m;
  int nm = gm / spatial, sp = gm % spatial;
  int oh = sp / OWW, ow = sp % OWW;
  __align__(16) u16 vals[8];
#pragma unroll
  for (int j = 0; j < 8; ++j) {
    int k = k0 + j;
    u16 v = 0;
    if (k < K) {
      int ic = k / 9, tap = k % 9;
      int ih = 2 * oh + tap / 3 - 1, iw = 2 * ow + tap % 3 - 1;
      if ((unsigned)ih < (unsigned)H && (unsigned)iw < (unsigned)W)
        v = NHWC ? in[((long)nm * H * W + ih * W + iw) * IC + ic]
                 : in[((long)nm * IC + ic) * H * W + ih * W + iw];
    }
    vals[j] = v;
  }
  *(uint4*)(patch + (long)m * KP + k0) = *(uint4*)vals;
}

// ---------------------------------------------------------------------------
// MFMA GEMM: out[m][n] = epilogue(sum_k A[m][k]*Wt[n][k]).
// EPI: 0=split-K fp32 partial; 1=bias+lrelu bf16; 2=conv BN+lrelu bf16
// ---------------------------------------------------------------------------
template <int EPI>
__global__ __launch_bounds__(256) void fc_mfma_kernel(
    const u16* __restrict__ A, const u16* __restrict__ Wt,
    const float* __restrict__ p0, const float* __restrict__ p1,
    const float* __restrict__ p2, u16* __restrict__ out,
    float* __restrict__ partial, int K, int N, int ksegLen, int nvalid) {
  __shared__ u16 As[64][72];
  __shared__ u16 Bs[64][72];
  int tid = threadIdx.x;
  int m0 = blockIdx.x * 64, n0 = blockIdx.y * 64;
  long kbase = (long)blockIdx.z * ksegLen;
  int row = tid >> 3;
  int seg = (tid & 7) * 8;
  const u16* ap0 = A + (long)(m0 + row) * K + kbase + seg;
  const u16* ap1 = A + (long)(m0 + row + 32) * K + kbase + seg;
  const u16* bp0 = Wt + (long)(n0 + row) * K + kbase + seg;
  const u16* bp1 = Wt + (long)(n0 + row + 32) * K + kbase + seg;
  uint4 ra0 = *(const uint4*)ap0;
  uint4 ra1 = *(const uint4*)ap1;
  uint4 rb0 = *(const uint4*)bp0;
  uint4 rb1 = *(const uint4*)bp1;
  int wv = tid >> 6, lane = tid & 63;
  int lr = lane & 15, q = lane >> 4;
  int mb = (wv >> 1) * 32, nb = (wv & 1) * 32;
  f32x4 acc[2][2] = {};
  for (int k0 = 0; k0 < ksegLen; k0 += 64) {
    *(uint4*)&As[row][seg] = ra0;
    *(uint4*)&As[row + 32][seg] = ra1;
    *(uint4*)&Bs[row][seg] = rb0;
    *(uint4*)&Bs[row + 32][seg] = rb1;
    __syncthreads();
    if (k0 + 64 < ksegLen) {
      ra0 = *(const uint4*)(ap0 + k0 + 64);
      ra1 = *(const uint4*)(ap1 + k0 + 64);
      rb0 = *(const uint4*)(bp0 + k0 + 64);
      rb1 = *(const uint4*)(bp1 + k0 + 64);
    }
#pragma unroll
    for (int kk = 0; kk < 64; kk += 32) {
      bf16x8 a0 = *(bf16x8*)&As[mb + lr][kk + q * 8];
      bf16x8 a1 = *(bf16x8*)&As[mb + 16 + lr][kk + q * 8];
      bf16x8 b0 = *(bf16x8*)&Bs[nb + lr][kk + q * 8];
      bf16x8 b1 = *(bf16x8*)&Bs[nb + 16 + lr][kk + q * 8];
      acc[0][0] = __builtin_amdgcn_mfma_f32_16x16x32_bf16(a0, b0, acc[0][0], 0, 0, 0);
      acc[0][1] = __builtin_amdgcn_mfma_f32_16x16x32_bf16(a0, b1, acc[0][1], 0, 0, 0);
      acc[1][0] = __builtin_amdgcn_mfma_f32_16x16x32_bf16(a1, b0, acc[1][0], 0, 0, 0);
      acc[1][1] = __builtin_amdgcn_mfma_f32_16x16x32_bf16(a1, b1, acc[1][1], 0, 0, 0);
    }
    __syncthreads();
  }
#pragma unroll
  for (int mi = 0; mi < 2; ++mi)
#pragma unroll
    for (int ni = 0; ni < 2; ++ni) {
      int col = n0 + nb + ni * 16 + lr;
      if (EPI == 2 && col >= nvalid) continue;
      float b0v = 0.f, scv = 1.f, shv = 0.f;
      if (EPI == 1) b0v = p0[col];
      if (EPI == 2) { b0v = p0[col]; scv = p1[col] * BNS; shv = p2[col]; }
#pragma unroll
      for (int r = 0; r < 4; ++r) {
        int grow = m0 + mb + mi * 16 + q * 4 + r;
        float y = acc[mi][ni][r];
        if (EPI == 0) {
          partial[((long)blockIdx.z * 256 + grow) * N + col] = y;
        } else if (EPI == 1) {
          out[(long)grow * N + col] = f2b(LRELU(y + b0v));
        } else {
          out[(long)grow * N + col] = f2b(LRELU((y + b0v) * scv + shv));
        }
      }
    }
}

// ---------------------------------------------------------------------------
// split-K reduce
// ---------------------------------------------------------------------------
__global__ __launch_bounds__(256) void fc_reduce_kernel(
    const float* __restrict__ partial, const float* __restrict__ bias,
    u16* __restrict__ out, int MN, int N, int S) {
  int i = blockIdx.x * 256 + threadIdx.x;
  if (i * 4 >= MN) return;
  float4 s = ((const float4*)partial)[i];
  for (int t = 1; t < S; ++t) {
    float4 p = ((const float4*)partial)[(long)t * (MN >> 2) + i];
    s.x += p.x; s.y += p.y; s.z += p.z; s.w += p.w;
  }
  int col = (i * 4) % N;
  float4 bv = *(const float4*)(bias + col);
  ushort4 o;
  o.x = f2b(LRELU(s.x + bv.x));
  o.y = f2b(LRELU(s.y + bv.y));
  o.z = f2b(LRELU(s.z + bv.z));
  o.w = f2b(LRELU(s.w + bv.w));
  ((ushort4*)out)[i] = o;
}

// ---------------------------------------------------------------------------
// Transposed conv via parity classes — WAVE-UNIFORM class (wave = class).
// Class work ratio is 1:2:2:4, and wave i always lands on SIMD i: without
// rotation every CU's SIMD3 gets ALL heavy (1,1) waves -> VALUBusy ceiling
// mean/max = 2.25/4 = 56% (measured 59%, r5). Per-block class rotation
// (bijective within block) statistically balances SIMD loads.
// bf16 LDS staging; rolled loops; named scalar accumulators.
// grid: (NTILEH * OCTOT/OCB, 256)
// ---------------------------------------------------------------------------
template <int IC, int OCTOT, int OCB, int IH, int IW, int TOH, int NTILEH>
__global__ __launch_bounds__(256) void convt_cls_kernel(
    const u16* __restrict__ in, const float* __restrict__ w,
    const float* __restrict__ cb, const float* __restrict__ bg,
    const float* __restrict__ bnb, u16* __restrict__ out) {
  constexpr int AA = TOH / 2;
  constexpr int IHT = AA + 1;
  constexpr int RW = IW + 4;
  constexpr int OH = 2 * IH, OW = 2 * IW;
  constexpr int BG = IW / 4;
  constexpr int OG = OCB / 4;
  constexpr int CLS = AA * BG * OG;
  __shared__ __align__(16) u16 in_s[IC * IHT * RW];
  __shared__ __align__(16) u16 w_s[9 * IC * OCB];
  int nm = blockIdx.y;
  int tile = blockIdx.x % NTILEH;
  int oc0 = (blockIdx.x / NTILEH) * OCB;
  int oh0 = tile * TOH;
  int ihb = oh0 >> 1;
  const u16* inb = in + (long)nm * IC * IH * IW;
  for (int e = threadIdx.x; e < IC * IHT * RW; e += 256) {
    int cw = e % RW;
    int r = (e / RW) % IHT;
    int ic = e / (RW * IHT);
    int ih = ihb + r;
    u16 v = 0;
    if (cw < IW && ih < IH) v = inb[(ic * IH + ih) * IW + cw];
    in_s[e] = v;
  }
  for (int e = threadIdx.x; e < 9 * IC * OCB; e += 256) {
    int ocl = e % OCB;
    int ic = (e / OCB) % IC;
    int khw = e / (OCB * IC);
    w_s[e] = f2b(w[(ic * OCTOT + oc0 + ocl) * 9 + khw]);
  }
  __syncthreads();
  // per-block class rotation: co-resident blocks (linear ids ~256 apart ->
  // nm differs by 64) get different rot via nm + (nm>>6) (65 == 1 mod 4)
  int rot = (blockIdx.x + nm + (nm >> 6)) & 3;
  int cls = ((threadIdx.x >> 6) + rot) & 3;  // wave-uniform, bijective
  int lane = threadIdx.x & 63;
  int p = cls >> 1, q = cls & 1;
#pragma unroll 1
  for (int rem = lane; rem < CLS; rem += 64) {
    int a = rem % AA;
    int t2 = rem / AA;
    int bgi = t2 % BG;
    int og = t2 / BG;
    int b0 = bgi * 4, oc = og * 4;
    float a00 = 0.f, a01 = 0.f, a02 = 0.f, a03 = 0.f;
    float a10 = 0.f, a11 = 0.f, a12 = 0.f, a13 = 0.f;
    float a20 = 0.f, a21 = 0.f, a22 = 0.f, a23 = 0.f;
    float a30 = 0.f, a31 = 0.f, a32 = 0.f, a33 = 0.f;
#pragma unroll 1
    for (int kh = 0; kh < 3; ++kh) {
      int th = p + 1 - kh;
      if (th & 1) continue;  // wave-uniform
      int r = a + (th >> 1);
      const u16* ib = &in_s[r * RW + b0];
      const u16* wb = &w_s[(kh * 3) * IC * OCB + oc];
      if (q == 0) {
#pragma unroll 1
        for (int ic = 0; ic < IC; ++ic) {
          float4 iv = b2f4(*(const ushort4*)(ib + ic * IHT * RW));
          float4 wv1 = b2f4(*(const ushort4*)(wb + (IC + ic) * OCB));  // kw=1
          FM16(iv.x, iv.y, iv.z, iv.w, wv1);
        }
      } else {
#pragma unroll 1
        for (int ic = 0; ic < IC; ++ic) {
          float4 iv = b2f4(*(const ushort4*)(ib + ic * IHT * RW));
          float x4 = b2f(ib[ic * IHT * RW + 4]);
          float4 wv2 = b2f4(*(const ushort4*)(wb + (2 * IC + ic) * OCB));  // kw=2
          FM16(iv.x, iv.y, iv.z, iv.w, wv2);
          float4 wv0 = b2f4(*(const ushort4*)(wb + ic * OCB));  // kw=0, shifted
          FM16(iv.y, iv.z, iv.w, x4, wv0);
        }
      }
    }
    int oh = oh0 + 2 * a + p;
    if (oh >= OH) continue;
    int ow0 = 2 * b0 + q;
#define CT_STJ(J, A0, A1, A2, A3)                                        \
    do {                                                                 \
      int o_ = oc0 + oc + (J);                                           \
      float c_ = cb[o_], s_ = bg[o_] * BNS, h_ = bnb[o_];                \
      u16* op_ = out + ((long)(nm * OCTOT + o_) * OH + oh) * OW + ow0;   \
      float y0_ = ((A0) + c_) * s_ + h_;                                 \
      float y1_ = ((A1) + c_) * s_ + h_;                                 \
      float y2_ = ((A2) + c_) * s_ + h_;                                 \
      float y3_ = ((A3) + c_) * s_ + h_;                                 \
      op_[0] = f2b(LRELU(y0_)); op_[2] = f2b(LRELU(y1_));                \
      op_[4] = f2b(LRELU(y2_)); op_[6] = f2b(LRELU(y3_));                \
    } while (0)
    CT_STJ(0, a00, a10, a20, a30);
    CT_STJ(1, a01, a11, a21, a31);
    CT_STJ(2, a02, a12, a22, a32);
    CT_STJ(3, a03, a13, a23, a33);
#undef CT_STJ
  }
}

// ---------------------------------------------------------------------------
// ct3 parity-class, wave-uniform class: 16->3, tanh, fp32 out (256,3,300,25)
// bf16 in_s (exact raw copy), fp32 w_s (tiny). Class rotation for SIMD
// balance. 12 named scalar accumulators; rolled loops; raw acc+bias staged
// to LDS; tanh deferred to coalesced float4 write-out.
// grid (4, 256)
// ---------------------------------------------------------------------------
__global__ __launch_bounds__(256) void convt3_cls_kernel(
    const u16* __restrict__ in, const float* __restrict__ w,
    const float* __restrict__ cb, float* __restrict__ out) {
  constexpr int IC = 16, IH = 152, IW = 16, TOH = 76;
  constexpr int AA = 38, IHT = 39, RW = 20, BG = 4, CLS = AA * BG;
  constexpr int CH = TOH * 25;  // 1900 f32 per channel tile
  __shared__ __align__(16) u16 in_s[IC * IHT * RW];
  __shared__ float w_s[9 * IC * 4];
  __shared__ __align__(16) float out_s[3 * CH];
  int nm = blockIdx.y;
  int oh0 = blockIdx.x * TOH;
  int ihb = oh0 >> 1;
  const u16* inb = in + (long)nm * IC * IH * IW;
  for (int e = threadIdx.x; e < IC * IHT * RW; e += 256) {
    int cw = e % RW;
    int r = (e / RW) % IHT;
    int ic = e / (RW * IHT);
    int ih = ihb + r;
    u16 v = 0;
    if (cw < IW && ih < IH) v = inb[(ic * IH + ih) * IW + cw];
    in_s[e] = v;
  }
  for (int e = threadIdx.x; e < 9 * IC * 4; e += 256) {
    int ocl = e % 4;
    int ic = (e / 4) % IC;
    int khw = e / 64;
    w_s[e] = (ocl < 3) ? w[(ic * 3 + ocl) * 9 + khw] : 0.f;
  }
  __syncthreads();
  float cb0 = cb[0], cb1 = cb[1], cb2 = cb[2];
  int rot = (blockIdx.x + nm + (nm >> 6)) & 3;
  int cls = ((threadIdx.x >> 6) + rot) & 3;  // wave-uniform, bijective
  int lane = threadIdx.x & 63;
  int p = cls >> 1, q = cls & 1;
#pragma unroll 1
  for (int rem = lane; rem < CLS; rem += 64) {
    int a = rem % AA;
    int bgi = rem / AA;
    int b0 = bgi * 4;
    float a0x = 0.f, a0y = 0.f, a0z = 0.f;
    float a1x = 0.f, a1y = 0.f, a1z = 0.f;
    float a2x = 0.f, a2y = 0.f, a2z = 0.f;
    float a3x = 0.f, a3y = 0.f, a3z = 0.f;
#pragma unroll 1
    for (int kh = 0; kh < 3; ++kh) {
      int th = p + 1 - kh;
      if (th & 1) continue;  // wave-uniform
      int r = a + (th >> 1);
      const u16* ib = &in_s[r * RW + b0];
      const float* wb = &w_s[(kh * 3) * IC * 4];
      if (q == 0) {
#pragma unroll 1
        for (int ic = 0; ic < IC; ++ic) {
          float4 iv = b2f4(*(const ushort4*)(ib + ic * IHT * RW));
          float4 wv1 = *(const float4*)(wb + (IC + ic) * 4);  // kw=1
          FM12(iv.x, iv.y, iv.z, iv.w, wv1);
        }
      } else {
#pragma unroll 1
        for (int ic = 0; ic < IC; ++ic) {
          float4 iv = b2f4(*(const ushort4*)(ib + ic * IHT * RW));
          float x4 = b2f(ib[ic * IHT * RW + 4]);
          float4 wv2 = *(const float4*)(wb + (2 * IC + ic) * 4);  // kw=2
          FM12(iv.x, iv.y, iv.z, iv.w, wv2);
          float4 wv0 = *(const float4*)(wb + ic * 4);  // kw=0, shifted
          FM12(iv.y, iv.z, iv.w, x4, wv0);
        }
      }
    }
    int ohl = 2 * a + p;  // local row in [0,76)
    int ow0 = 2 * b0 + q;
#define CT3_STB(B, AX, AY, AZ)                                           \
    do {                                                                 \
      int ow_ = ow0 + 2 * (B);                                           \
      if (ow_ < 25) {                                                    \
        out_s[ohl * 25 + ow_] = (AX) + cb0;                              \
        out_s[CH + ohl * 25 + ow_] = (AY) + cb1;                         \
        out_s[2 * CH + ohl * 25 + ow_] = (AZ) + cb2;                     \
      }                                                                  \
    } while (0)
    CT3_STB(0, a0x, a0y, a0z);
    CT3_STB(1, a1x, a1y, a1z);
    CT3_STB(2, a2x, a2y, a2z);
    CT3_STB(3, a3x, a3y, a3z);
#undef CT3_STB
  }
  __syncthreads();
  // coalesced write-out with deferred tanh (rows beyond oh=300 dropped)
  int rows = 300 - oh0;
  if (rows > TOH) rows = TOH;
  int cnt = rows * 25;         // 1900 or 1800, both mult of 4
  int tot4 = (3 * cnt) >> 2;
  for (int e4 = threadIdx.x; e4 < tot4; e4 += 256) {
    int e = e4 << 2;
    int j = e / cnt;
    int r = e - j * cnt;
    float4 v = *(const float4*)(out_s + j * CH + r);
    v.x = ftanh(v.x); v.y = ftanh(v.y); v.z = ftanh(v.z); v.w = ftanh(v.w);
    *(float4*)(out + ((long)(nm * 3 + j) * 300 + oh0) * 25 + r) = v;
  }
}

// ---------------------------------------------------------------------------
// segmented scan over t
// ---------------------------------------------------------------------------
__global__ __launch_bounds__(256) void scan_kernel(
    const float* __restrict__ dec, const float* __restrict__ x0,
    const unsigned char* __restrict__ z, float* __restrict__ out) {
  int idx = blockIdx.x * 256 + threadIdx.x;
  if (idx >= 256 * 75) return;
  int v = idx % 25;
  int c = (idx / 25) % 3;
  int nm = idx / 75;
  int n = nm >> 1, m = nm & 1;
  const float* db = dec + ((long)(nm * 3 + c) * 300) * 25 + v;
  const unsigned char* zb = z + nm * 300;
  float* ob = out + (((long)(n * 3 + c) * 300) * 25 + v) * 2 + m;
  float x0v = x0[(nm * 3 + c) * 25 + v];
  float carry = 0.f;
  for (int t0 = 0; t0 < 300; t0 += 10) {
    float vals[10];
#pragma unroll
    for (int i = 0; i < 10; ++i) vals[i] = db[(t0 + i) * 25];
#pragma unroll
    for (int i = 0; i < 10; ++i) {
      int t = t0 + i;
      float d = (t == 0) ? x0v : vals[i];
      carry = zb[t] ? 0.f : (d + carry);
      ob[(long)t * 50] = carry;
    }
  }
}

// ---------------------------------------------------------------------------
extern "C" void kernel_launch(void* const* d_in, const int* in_sizes, int n_in,
                              void* d_out, int out_size, void* d_ws, size_t ws_size,
                              hipStream_t stream) {
  const float* x     = (const float*)d_in[0];
  const float* dbn_g = (const float*)d_in[1];
  const float* dbn_b = (const float*)d_in[2];
  const float* c1_w  = (const float*)d_in[3];
  const float* c1_b  = (const float*)d_in[4];
  const float* bn1_g = (const float*)d_in[5];
  const float* bn1_b = (const float*)d_in[6];
  const float* c2_w  = (const float*)d_in[7];
  const float* c2_b  = (const float*)d_in[8];
  const float* bn2_g = (const float*)d_in[9];
  const float* bn2_b = (const float*)d_in[10];
  const float* c3_w  = (const float*)d_in[11];
  const float* c3_b  = (const float*)d_in[12];
  const float* bn3_g = (const float*)d_in[13];
  const float* bn3_b = (const float*)d_in[14];
  const float* fc1_w = (const float*)d_in[15];
  const float* fc1_b = (const float*)d_in[16];
  const float* fc2_w = (const float*)d_in[17];
  const float* fc2_b = (const float*)d_in[18];
  const float* fc3_w = (const float*)d_in[19];
  const float* fc3_b = (const float*)d_in[20];
  const float* fc4_w = (const float*)d_in[21];
  const float* fc4_b = (const float*)d_in[22];
  const float* ct1_w = (const float*)d_in[23];
  const float* ct1_b = (const float*)d_in[24];
  const float* bn4_g = (const float*)d_in[25];
  const float* bn4_b = (const float*)d_in[26];
  const float* ct2_w = (const float*)d_in[27];
  const float* ct2_b = (const float*)d_in[28];
  const float* bn5_g = (const float*)d_in[29];
  const float* bn5_b = (const float*)d_in[30];
  const float* ct3_w = (const float*)d_in[31];
  const float* ct3_b = (const float*)d_in[32];
  float* out = (float*)d_out;

  // ---- workspace (liveness-overlapped arena, ~85.7 MB) ----
  char* ws = (char*)d_ws;
  unsigned char* zbuf = (unsigned char*)ws;             // 76,800
  float* x0 = (float*)(ws + 131072);
  // A (23.2 MB): dm -> wbA(fc1) -> wbA(fc4) -> ct3o
  char* slotA = ws + 262144;
  float* dm   = (float*)slotA;
  u16*   wbA  = (u16*)slotA;
  float* ct3o = (float*)slotA;
  // B (20.97 MB): c1o -> ct2o
  char* slotB = ws + 23461888;
  u16* c1o  = (u16*)slotB;
  u16* ct2o = (u16*)slotB;
  // P (25.8 MB): patch2 halves / patch3 -> partial -> ct1o
  char* slotP = ws + 44433408;
  u16*   patch   = (u16*)slotP;
  float* partial = (float*)slotP;
  u16*   ct1o    = (u16*)slotP;
  // D (8.7 MB): c2o -> f4
  char* slotD = ws + 70254592;
  u16* c2o = (u16*)slotD;
  u16* f4  = (u16*)slotD;
  // E (5 MB): c3o
  u16* c3o = (u16*)(ws + 78954496);
  // G: small buffers
  u16* wb2   = (u16*)(ws + 83968000);
  u16* wb3   = (u16*)(ws + 84230144);
  u16* f1    = (u16*)(ws + 84492288);
  u16* f2    = (u16*)(ws + 85016576);
  u16* f3    = (u16*)(ws + 85082112);
  u16* w2pad = (u16*)(ws + 85606400);
  u16* w3pad = (u16*)(ws + 85630976);

  prep_kernel<<<22500, 256, 0, stream>>>(x, dbn_g, dbn_b, dm, x0);
  zflag_kernel<<<19200, 256, 0, stream>>>(dm, zbuf);

  // conv1 (fp32 dm -> bf16 c1o NCHW)
  conv_tiled_kernel<float, 3, 16, 16, 8, 299, 25, 150, 13, 30, 5>
      <<<dim3(5, 256), 256, 0, stream>>>(dm, c1_w, c1_b, bn1_g, bn1_b, c1o);

  // dm now dead -> cast fc1 weights (permuted to NHWC k-order) into slot A
  wcast_fc1_kernel<<<38912, 256, 0, stream>>>(fc1_w, wbA);
  cast_kernel<<<128, 256, 0, stream>>>(fc2_w, wb2, 32768);
  cast_kernel<<<128, 256, 0, stream>>>(fc3_w, wb3, 32768);
  wpad_kernel<<<48, 256, 0, stream>>>(c2_w, w2pad, 32, 144, 192);
  wpad_kernel<<<80, 256, 0, stream>>>(c3_w, w3pad, 64, 288, 320);

  // conv2 = im2col + MFMA GEMM, two nm-halves (M=67200 each, K=192, N=32)
  for (int h = 0; h < 2; ++h) {
    im2col_kernel<16, 150, 13, 7, 144, 192, false><<<6300, 256, 0, stream>>>(
        c1o, patch, h * 67200, 525, 67200 * 24);
    fc_mfma_kernel<2><<<dim3(1050, 1, 1), 256, 0, stream>>>(
        patch, w2pad, c2_b, bn2_g, bn2_b, c2o + (long)h * 67200 * 32, nullptr,
        192, 32, 192, 32);
  }
  // conv3 = im2col + GEMM (M=38912, K=320, N=64), out NHWC = fc1's A order
  im2col_kernel<32, 75, 7, 4, 288, 320, true><<<6080, 256, 0, stream>>>(
      c2o, patch, 0, 152, 38912 * 40);
  fc_mfma_kernel<2><<<dim3(608, 1, 1), 256, 0, stream>>>(
      patch, w3pad, c3_b, bn3_g, bn3_b, c3o, nullptr, 320, 64, 320, 64);

  // fc1 split-K=8
  fc_mfma_kernel<0><<<dim3(4, 16, 8), 256, 0, stream>>>(
      c3o, wbA, nullptr, nullptr, nullptr, nullptr, partial, 9728, 1024, 1216, 0);
  fc_reduce_kernel<<<256, 256, 0, stream>>>(partial, fc1_b, f1, 262144, 1024, 8);
  cast_kernel<<<9728, 256, 0, stream>>>(fc4_w, wbA, 2490368);
  // fc2 split-K=16
  fc_mfma_kernel<0><<<dim3(4, 2, 16), 256, 0, stream>>>(
      f1, wb2, nullptr, nullptr, nullptr, nullptr, partial, 1024, 128, 64, 0);
  fc_reduce_kernel<<<32, 256, 0, stream>>>(partial, fc2_b, f2, 32768, 128, 16);
  // fc3 split-K=2
  fc_mfma_kernel<0><<<dim3(4, 16, 2), 256, 0, stream>>>(
      f2, wb3, nullptr, nullptr, nullptr, nullptr, partial, 128, 1024, 64, 0);
  fc_reduce_kernel<<<256, 256, 0, stream>>>(partial, fc3_b, f3, 262144, 1024, 2);
  // fc4 direct (N-order = NCHW flat, feeds ct1)
  fc_mfma_kernel<1><<<dim3(4, 152, 1), 256, 0, stream>>>(
      f3, wbA, fc4_b, nullptr, nullptr, f4, nullptr, 1024, 9728, 1024, 9728);

  // decoder: parity-class convT (bf16 LDS, rolled loops, class rotation)
  convt_cls_kernel<64, 32, 16, 38, 4, 38, 2>
      <<<dim3(4, 256), 256, 0, stream>>>(f4, ct1_w, ct1_b, bn4_g, bn4_b, ct1o);
  convt_cls_kernel<32, 16, 16, 76, 8, 38, 4>
      <<<dim3(4, 256), 256, 0, stream>>>(ct1o, ct2_w, ct2_b, bn5_g, bn5_b, ct2o);
  convt3_cls_kernel<<<dim3(4, 256), 256, 0, stream>>>(ct2o, ct3_w, ct3_b, ct3o);

  scan_kernel<<<75, 256, 0, stream>>>(ct3o, x0, zbuf, out);
}

// Round 9
// 618.254 us; speedup vs baseline: 1.0994x; 1.0994x over previous
//
#include <hip/hip_runtime.h>
#include <math.h>

#define LRELU(y) ((y) > 0.f ? (y) : 0.01f * (y))
__device__ __constant__ float BNS = 0.99999500003749969f; // 1/sqrt(1+1e-5)

typedef unsigned short u16;
typedef __attribute__((ext_vector_type(8))) short bf16x8;
typedef __attribute__((ext_vector_type(4))) float f32x4;

__device__ inline u16 f2b(float f) {
  union { float f; unsigned u; } x; x.f = f;
  return (u16)((x.u + 0x7FFFu + ((x.u >> 16) & 1u)) >> 16);
}
__device__ inline float b2f(u16 b) {
  union { unsigned u; float f; } x; x.u = ((unsigned)b) << 16;
  return x.f;
}
__device__ inline float4 b2f4(ushort4 u) {
  float4 r;
  r.x = b2f(u.x); r.y = b2f(u.y); r.z = b2f(u.z); r.w = b2f(u.w);
  return r;
}
__device__ inline float ldv(const float* p) { return *p; }
__device__ inline float ldv(const u16* p) { return b2f(*p); }

// fast tanh: 1 - 2/(e^{2|x|}+1), sign restored. exp-based, no libcall.
__device__ inline float ftanh(float x) {
  float e = __expf(2.0f * fabsf(x));
  float t = 1.0f - 2.0f / (e + 1.0f);
  return x < 0.f ? -t : t;
}

// Named-scalar FMA expansions (VGPR-only accumulators).
#define FM16(I0, I1, I2, I3, WV)                                        \
  a00 += (I0) * (WV).x; a01 += (I0) * (WV).y;                           \
  a02 += (I0) * (WV).z; a03 += (I0) * (WV).w;                           \
  a10 += (I1) * (WV).x; a11 += (I1) * (WV).y;                           \
  a12 += (I1) * (WV).z; a13 += (I1) * (WV).w;                           \
  a20 += (I2) * (WV).x; a21 += (I2) * (WV).y;                           \
  a22 += (I2) * (WV).z; a23 += (I2) * (WV).w;                           \
  a30 += (I3) * (WV).x; a31 += (I3) * (WV).y;                           \
  a32 += (I3) * (WV).z; a33 += (I3) * (WV).w;

#define FM12(I0, I1, I2, I3, WV)                                        \
  a0x += (I0) * (WV).x; a0y += (I0) * (WV).y; a0z += (I0) * (WV).z;     \
  a1x += (I1) * (WV).x; a1y += (I1) * (WV).y; a1z += (I1) * (WV).z;     \
  a2x += (I2) * (WV).x; a2y += (I2) * (WV).y; a2z += (I2) * (WV).z;     \
  a3x += (I3) * (WV).x; a3y += (I3) * (WV).y; a3z += (I3) * (WV).z;

// ---------------------------------------------------------------------------
// Static LPT schedules for parity-class convT: balance the {1,2,2,4}
// class costs across the 4 waves at 64-item chunk granularity (cost model:
// whole wave executes each chunk-iteration, so chunk cost = class weight).
// Entry = {class, i0, i1}.
// CLS=76 (ct1): makespan 8->5. CLS=152 (ct2 AND ct3): makespan 12->7.
// [r8 lesson: ct2's CLS is 19*2*4=152, NOT 304 — AA=TOH/2=19.]
// ---------------------------------------------------------------------------
__device__ __constant__ short SCH76[4][2][3] = {
  {{3, 0, 64}, {0, 0, 64}},
  {{3, 64, 76}, {0, 64, 76}},
  {{1, 0, 64}, {2, 0, 64}},
  {{1, 64, 76}, {2, 64, 76}},
};
__device__ __constant__ short SCH152[4][3][3] = {
  {{3, 0, 64}, {1, 128, 152}, {0, 0, 64}},
  {{3, 64, 128}, {2, 0, 64}, {0, 64, 128}},
  {{3, 128, 152}, {2, 64, 128}, {0, 128, 152}},
  {{1, 0, 64}, {1, 64, 128}, {2, 128, 152}},
};

// ---------------------------------------------------------------------------
// cast fp32 -> bf16
// ---------------------------------------------------------------------------
__global__ __launch_bounds__(256) void cast_kernel(
    const float* __restrict__ s, u16* __restrict__ d, int n4) {
  int i = blockIdx.x * 256 + threadIdx.x;
  if (i >= n4) return;
  float4 v = ((const float4*)s)[i];
  ushort4 o;
  o.x = f2b(v.x); o.y = f2b(v.y); o.z = f2b(v.z); o.w = f2b(v.w);
  ((ushort4*)d)[i] = o;
}

// fc1 weight: cast + permute columns k=oc*152+sp -> k'=sp*64+oc
__global__ __launch_bounds__(256) void wcast_fc1_kernel(
    const float* __restrict__ w, u16* __restrict__ wp) {
  int idx = blockIdx.x * 256 + threadIdx.x;
  if (idx >= 1024 * 9728) return;
  int n = idx / 9728, kp = idx % 9728;
  int sp = kp >> 6, oc = kp & 63;
  wp[idx] = f2b(w[(long)n * 9728 + oc * 152 + sp]);
}

// conv weight -> padded bf16 (64 x KP)
__global__ __launch_bounds__(256) void wpad_kernel(
    const float* __restrict__ w, u16* __restrict__ wp, int OC, int K, int KP) {
  int idx = blockIdx.x * 256 + threadIdx.x;
  if (idx >= 64 * KP) return;
  int row = idx / KP, col = idx % KP;
  wp[idx] = (row < OC && col < K) ? f2b(w[row * K + col]) : (u16)0;
}

// ---------------------------------------------------------------------------
// prep: x (128,3,300,25,2) -> dm (256,3,299,25) fp32, x0 (256,3,25) fp32
// ---------------------------------------------------------------------------
__global__ __launch_bounds__(256) void prep_kernel(
    const float* __restrict__ x, const float* __restrict__ g,
    const float* __restrict__ b, float* __restrict__ dm,
    float* __restrict__ x0) {
  int idx = blockIdx.x * 256 + threadIdx.x;
  if (idx >= 256 * 3 * 300 * 25) return;
  int v = idx % 25;
  int t = (idx / 25) % 300;
  int c = (idx / (25 * 300)) % 3;
  int nm = idx / (25 * 300 * 3);
  int n = nm >> 1, m = nm & 1;
  int ch = m * 75 + v * 3 + c;
  float s = g[ch] * BNS, bb = b[ch];
  long xi = (((long)(n * 3 + c) * 300 + t) * 25 + v) * 2 + m;
  float xm_t = x[xi] * s + bb;
  if (t == 0) x0[(nm * 3 + c) * 25 + v] = xm_t;
  if (t < 299) {
    float xm_t1 = x[xi + 50] * s + bb;
    dm[((nm * 3 + c) * 299 + t) * 25 + v] = xm_t1 - xm_t;
  }
}

// ---------------------------------------------------------------------------
// z flags: one wave per (nm,t)
// ---------------------------------------------------------------------------
__global__ __launch_bounds__(256) void zflag_kernel(
    const float* __restrict__ dm, unsigned char* __restrict__ z) {
  int gw = blockIdx.x * 4 + (threadIdx.x >> 6);
  if (gw >= 256 * 300) return;
  int lane = threadIdx.x & 63;
  int t = gw % 300, nm = gw / 300;
  bool nz = false;
  if (t < 299) {
    const float* base = dm + (long)nm * 3 * 299 * 25 + t * 25;
    if (lane < 75) {
      int c = lane / 25, v = lane % 25;
      nz = base[c * 299 * 25 + v] != 0.f;
    }
    int l2 = lane + 64;
    if (l2 < 75) {
      int c = l2 / 25, v = l2 % 25;
      nz = nz || (base[c * 299 * 25 + v] != 0.f);
    }
  }
  unsigned long long mask = __ballot(nz);
  if (lane == 0) z[nm * 300 + t] = (unsigned char)((t < 299) && (mask == 0ull));
}

// ---------------------------------------------------------------------------
// conv1 (VALU tiled, fp32 in, bf16 out)
// ---------------------------------------------------------------------------
template <typename TI, int IC, int OC, int OCB, int ACC, int H, int W, int OH,
          int OW, int TOH, int NTILE>
__global__ __launch_bounds__(256) void conv_tiled_kernel(
    const TI* __restrict__ in, const float* __restrict__ w,
    const float* __restrict__ cb, const float* __restrict__ bg,
    const float* __restrict__ bnb, u16* __restrict__ out) {
  constexpr int IHT = 2 * TOH + 1;
  constexpr int RL = W + 2;
  __shared__ float in_s[IC * IHT * RL];
  __shared__ float w_s[9 * IC * OCB];
  int bx = blockIdx.x;
  int nm = blockIdx.y;
  int tile = bx % NTILE;
  int oc0 = (bx / NTILE) * OCB;
  int oh0 = tile * TOH;
  int ih0 = 2 * oh0 - 1;
  const TI* inb = in + (long)nm * IC * H * W;
  for (int e = threadIdx.x; e < IC * IHT * RL; e += 256) {
    int c = e % RL;
    int r = (e / RL) % IHT;
    int ic = e / (RL * IHT);
    int ih = ih0 + r, iw = c - 1;
    float v = 0.f;
    if (ih >= 0 && ih < H && iw >= 0 && iw < W) v = ldv(&inb[(ic * H + ih) * W + iw]);
    in_s[e] = v;
  }
  for (int e = threadIdx.x; e < 9 * IC * OCB; e += 256) {
    int ocl = e % OCB;
    int ic = (e / OCB) % IC;
    int khw = e / (OCB * IC);
    int kh = khw / 3, kw = khw % 3;
    w_s[e] = w[(((oc0 + ocl) * IC + ic) * 3 + kh) * 3 + kw];
  }
  __syncthreads();
  constexpr int NPOS = TOH * OW;
  constexpr int NWI = NPOS * (OCB / ACC);
  for (int wi = threadIdx.x; wi < NWI; wi += 256) {
    int pos = wi % NPOS;
    int jb = (wi / NPOS) * ACC;
    int ow = pos % OW;
    int oh_l = pos / OW;
    int oh = oh0 + oh_l;
    if (oh >= OH) continue;
    float acc[ACC];
#pragma unroll
    for (int j = 0; j < ACC; ++j) acc[j] = 0.f;
    for (int kh = 0; kh < 3; ++kh) {
      int r = 2 * oh_l + kh;
      for (int kw = 0; kw < 3; ++kw) {
        int cc = 2 * ow + kw;
        const float* ip = &in_s[r * RL + cc];
        const float* wp = &w_s[(kh * 3 + kw) * IC * OCB + jb];
        for (int ic = 0; ic < IC; ++ic) {
          float a = ip[ic * IHT * RL];
#pragma unroll
          for (int j = 0; j < ACC; ++j) acc[j] += a * wp[ic * OCB + j];
        }
      }
    }
#pragma unroll
    for (int j = 0; j < ACC; ++j) {
      int oc = oc0 + jb + j;
      float y = (acc[j] + cb[oc]) * (bg[oc] * BNS) + bnb[oc];
      out[((long)nm * OC + oc) * OH * OW + oh * OW + ow] = f2b(LRELU(y));
    }
  }
}

// ---------------------------------------------------------------------------
// im2col: build bf16 patch (m, KP), stride-2, pad 1, 3x3.
// ---------------------------------------------------------------------------
template <int IC, int H, int W, int OWW, int K, int KP, bool NHWC>
__global__ __launch_bounds__(256) void im2col_kernel(
    const u16* __restrict__ in, u16* __restrict__ patch, int m_off,
    int spatial, int n_threads) {
  int idx = blockIdx.x * 256 + threadIdx.x;
  if (idx >= n_threads) return;
  constexpr int KP8 = KP / 8;
  int m = idx / KP8;
  int k0 = (idx % KP8) * 8;
  int gm = m_off + m;
  int nm = gm / spatial, sp = gm % spatial;
  int oh = sp / OWW, ow = sp % OWW;
  __align__(16) u16 vals[8];
#pragma unroll
  for (int j = 0; j < 8; ++j) {
    int k = k0 + j;
    u16 v = 0;
    if (k < K) {
      int ic = k / 9, tap = k % 9;
      int ih = 2 * oh + tap / 3 - 1, iw = 2 * ow + tap % 3 - 1;
      if ((unsigned)ih < (unsigned)H && (unsigned)iw < (unsigned)W)
        v = NHWC ? in[((long)nm * H * W + ih * W + iw) * IC + ic]
                 : in[((long)nm * IC + ic) * H * W + ih * W + iw];
    }
    vals[j] = v;
  }
  *(uint4*)(patch + (long)m * KP + k0) = *(uint4*)vals;
}

// ---------------------------------------------------------------------------
// MFMA GEMM: out[m][n] = epilogue(sum_k A[m][k]*Wt[n][k]).
// EPI: 0=split-K fp32 partial; 1=bias+lrelu bf16; 2=conv BN+lrelu bf16
// ---------------------------------------------------------------------------
template <int EPI>
__global__ __launch_bounds__(256) void fc_mfma_kernel(
    const u16* __restrict__ A, const u16* __restrict__ Wt,
    const float* __restrict__ p0, const float* __restrict__ p1,
    const float* __restrict__ p2, u16* __restrict__ out,
    float* __restrict__ partial, int K, int N, int ksegLen, int nvalid) {
  __shared__ u16 As[64][72];
  __shared__ u16 Bs[64][72];
  int tid = threadIdx.x;
  int m0 = blockIdx.x * 64, n0 = blockIdx.y * 64;
  long kbase = (long)blockIdx.z * ksegLen;
  int row = tid >> 3;
  int seg = (tid & 7) * 8;
  const u16* ap0 = A + (long)(m0 + row) * K + kbase + seg;
  const u16* ap1 = A + (long)(m0 + row + 32) * K + kbase + seg;
  const u16* bp0 = Wt + (long)(n0 + row) * K + kbase + seg;
  const u16* bp1 = Wt + (long)(n0 + row + 32) * K + kbase + seg;
  uint4 ra0 = *(const uint4*)ap0;
  uint4 ra1 = *(const uint4*)ap1;
  uint4 rb0 = *(const uint4*)bp0;
  uint4 rb1 = *(const uint4*)bp1;
  int wv = tid >> 6, lane = tid & 63;
  int lr = lane & 15, q = lane >> 4;
  int mb = (wv >> 1) * 32, nb = (wv & 1) * 32;
  f32x4 acc[2][2] = {};
  for (int k0 = 0; k0 < ksegLen; k0 += 64) {
    *(uint4*)&As[row][seg] = ra0;
    *(uint4*)&As[row + 32][seg] = ra1;
    *(uint4*)&Bs[row][seg] = rb0;
    *(uint4*)&Bs[row + 32][seg] = rb1;
    __syncthreads();
    if (k0 + 64 < ksegLen) {
      ra0 = *(const uint4*)(ap0 + k0 + 64);
      ra1 = *(const uint4*)(ap1 + k0 + 64);
      rb0 = *(const uint4*)(bp0 + k0 + 64);
      rb1 = *(const uint4*)(bp1 + k0 + 64);
    }
#pragma unroll
    for (int kk = 0; kk < 64; kk += 32) {
      bf16x8 a0 = *(bf16x8*)&As[mb + lr][kk + q * 8];
      bf16x8 a1 = *(bf16x8*)&As[mb + 16 + lr][kk + q * 8];
      bf16x8 b0 = *(bf16x8*)&Bs[nb + lr][kk + q * 8];
      bf16x8 b1 = *(bf16x8*)&Bs[nb + 16 + lr][kk + q * 8];
      acc[0][0] = __builtin_amdgcn_mfma_f32_16x16x32_bf16(a0, b0, acc[0][0], 0, 0, 0);
      acc[0][1] = __builtin_amdgcn_mfma_f32_16x16x32_bf16(a0, b1, acc[0][1], 0, 0, 0);
      acc[1][0] = __builtin_amdgcn_mfma_f32_16x16x32_bf16(a1, b0, acc[1][0], 0, 0, 0);
      acc[1][1] = __builtin_amdgcn_mfma_f32_16x16x32_bf16(a1, b1, acc[1][1], 0, 0, 0);
    }
    __syncthreads();
  }
#pragma unroll
  for (int mi = 0; mi < 2; ++mi)
#pragma unroll
    for (int ni = 0; ni < 2; ++ni) {
      int col = n0 + nb + ni * 16 + lr;
      if (EPI == 2 && col >= nvalid) continue;
      float b0v = 0.f, scv = 1.f, shv = 0.f;
      if (EPI == 1) b0v = p0[col];
      if (EPI == 2) { b0v = p0[col]; scv = p1[col] * BNS; shv = p2[col]; }
#pragma unroll
      for (int r = 0; r < 4; ++r) {
        int grow = m0 + mb + mi * 16 + q * 4 + r;
        float y = acc[mi][ni][r];
        if (EPI == 0) {
          partial[((long)blockIdx.z * 256 + grow) * N + col] = y;
        } else if (EPI == 1) {
          out[(long)grow * N + col] = f2b(LRELU(y + b0v));
        } else {
          out[(long)grow * N + col] = f2b(LRELU((y + b0v) * scv + shv));
        }
      }
    }
}

// ---------------------------------------------------------------------------
// split-K reduce
// ---------------------------------------------------------------------------
__global__ __launch_bounds__(256) void fc_reduce_kernel(
    const float* __restrict__ partial, const float* __restrict__ bias,
    u16* __restrict__ out, int MN, int N, int S) {
  int i = blockIdx.x * 256 + threadIdx.x;
  if (i * 4 >= MN) return;
  float4 s = ((const float4*)partial)[i];
  for (int t = 1; t < S; ++t) {
    float4 p = ((const float4*)partial)[(long)t * (MN >> 2) + i];
    s.x += p.x; s.y += p.y; s.z += p.z; s.w += p.w;
  }
  int col = (i * 4) % N;
  float4 bv = *(const float4*)(bias + col);
  ushort4 o;
  o.x = f2b(LRELU(s.x + bv.x));
  o.y = f2b(LRELU(s.y + bv.y));
  o.z = f2b(LRELU(s.z + bv.z));
  o.w = f2b(LRELU(s.w + bv.w));
  ((ushort4*)out)[i] = o;
}

// ---------------------------------------------------------------------------
// Transposed conv via parity classes, LPT-balanced across waves.
// Each wave runs a static schedule of (class, item-range) segments (class is
// wave-uniform per segment). Balances the {1,2,2,4} class costs: makespan
// 8->5 (ct1 CLS=76), 12->7 (ct2 CLS=152). bf16 LDS staging; rolled loops;
// named scalars. grid: (NTILEH * OCTOT/OCB, 256)
// ---------------------------------------------------------------------------
template <int IC, int OCTOT, int OCB, int IH, int IW, int TOH, int NTILEH>
__global__ __launch_bounds__(256) void convt_cls_kernel(
    const u16* __restrict__ in, const float* __restrict__ w,
    const float* __restrict__ cb, const float* __restrict__ bg,
    const float* __restrict__ bnb, u16* __restrict__ out) {
  constexpr int AA = TOH / 2;
  constexpr int IHT = AA + 1;
  constexpr int RW = IW + 4;
  constexpr int OH = 2 * IH, OW = 2 * IW;
  constexpr int BG = IW / 4;
  constexpr int OG = OCB / 4;
  constexpr int CLS = AA * BG * OG;
  static_assert(CLS == 76 || CLS == 152, "schedule table missing");
  constexpr int NSEG = (CLS == 76) ? 2 : 3;
  __shared__ __align__(16) u16 in_s[IC * IHT * RW];
  __shared__ __align__(16) u16 w_s[9 * IC * OCB];
  int nm = blockIdx.y;
  int tile = blockIdx.x % NTILEH;
  int oc0 = (blockIdx.x / NTILEH) * OCB;
  int oh0 = tile * TOH;
  int ihb = oh0 >> 1;
  const u16* inb = in + (long)nm * IC * IH * IW;
  for (int e = threadIdx.x; e < IC * IHT * RW; e += 256) {
    int cw = e % RW;
    int r = (e / RW) % IHT;
    int ic = e / (RW * IHT);
    int ih = ihb + r;
    u16 v = 0;
    if (cw < IW && ih < IH) v = inb[(ic * IH + ih) * IW + cw];
    in_s[e] = v;
  }
  for (int e = threadIdx.x; e < 9 * IC * OCB; e += 256) {
    int ocl = e % OCB;
    int ic = (e / OCB) % IC;
    int khw = e / (OCB * IC);
    w_s[e] = f2b(w[(ic * OCTOT + oc0 + ocl) * 9 + khw]);
  }
  __syncthreads();
  int wvid = threadIdx.x >> 6;
  int lane = threadIdx.x & 63;
  const short(*sch)[3] = (CLS == 76) ? SCH76[wvid] : SCH152[wvid];
#pragma unroll 1
  for (int s = 0; s < NSEG; ++s) {
    int c = sch[s][0];
    int i0 = sch[s][1], i1 = sch[s][2];
    int p = c >> 1, q = c & 1;
#pragma unroll 1
    for (int rem = i0 + lane; rem < i1; rem += 64) {
      int a = rem % AA;
      int t2 = rem / AA;
      int bgi = t2 % BG;
      int og = t2 / BG;
      int b0 = bgi * 4, oc = og * 4;
      float a00 = 0.f, a01 = 0.f, a02 = 0.f, a03 = 0.f;
      float a10 = 0.f, a11 = 0.f, a12 = 0.f, a13 = 0.f;
      float a20 = 0.f, a21 = 0.f, a22 = 0.f, a23 = 0.f;
      float a30 = 0.f, a31 = 0.f, a32 = 0.f, a33 = 0.f;
#pragma unroll 1
      for (int kh = 0; kh < 3; ++kh) {
        int th = p + 1 - kh;
        if (th & 1) continue;  // wave-uniform
        int r = a + (th >> 1);
        const u16* ib = &in_s[r * RW + b0];
        const u16* wb = &w_s[(kh * 3) * IC * OCB + oc];
        if (q == 0) {
#pragma unroll 1
          for (int ic = 0; ic < IC; ++ic) {
            float4 iv = b2f4(*(const ushort4*)(ib + ic * IHT * RW));
            float4 wv1 = b2f4(*(const ushort4*)(wb + (IC + ic) * OCB));  // kw=1
            FM16(iv.x, iv.y, iv.z, iv.w, wv1);
          }
        } else {
#pragma unroll 1
          for (int ic = 0; ic < IC; ++ic) {
            float4 iv = b2f4(*(const ushort4*)(ib + ic * IHT * RW));
            float x4 = b2f(ib[ic * IHT * RW + 4]);
            float4 wv2 = b2f4(*(const ushort4*)(wb + (2 * IC + ic) * OCB));  // kw=2
            FM16(iv.x, iv.y, iv.z, iv.w, wv2);
            float4 wv0 = b2f4(*(const ushort4*)(wb + ic * OCB));  // kw=0, shifted
            FM16(iv.y, iv.z, iv.w, x4, wv0);
          }
        }
      }
      int oh = oh0 + 2 * a + p;
      if (oh >= OH) continue;
      int ow0 = 2 * b0 + q;
#define CT_STJ(J, A0, A1, A2, A3)                                        \
      do {                                                               \
        int o_ = oc0 + oc + (J);                                         \
        float c_ = cb[o_], s_ = bg[o_] * BNS, h_ = bnb[o_];              \
        u16* op_ = out + ((long)(nm * OCTOT + o_) * OH + oh) * OW + ow0; \
        float y0_ = ((A0) + c_) * s_ + h_;                               \
        float y1_ = ((A1) + c_) * s_ + h_;                               \
        float y2_ = ((A2) + c_) * s_ + h_;                               \
        float y3_ = ((A3) + c_) * s_ + h_;                               \
        op_[0] = f2b(LRELU(y0_)); op_[2] = f2b(LRELU(y1_));              \
        op_[4] = f2b(LRELU(y2_)); op_[6] = f2b(LRELU(y3_));              \
      } while (0)
      CT_STJ(0, a00, a10, a20, a30);
      CT_STJ(1, a01, a11, a21, a31);
      CT_STJ(2, a02, a12, a22, a32);
      CT_STJ(3, a03, a13, a23, a33);
#undef CT_STJ
    }
  }
}

// ---------------------------------------------------------------------------
// ct3 parity-class, LPT-balanced (CLS=152, makespan 12->7): 16->3, tanh,
// fp32 out (256,3,300,25). bf16 in_s; fp32 w_s; named scalar accumulators;
// rolled loops; raw acc+bias staged to LDS; tanh deferred to coalesced
// float4 write-out. grid (4, 256)
// ---------------------------------------------------------------------------
__global__ __launch_bounds__(256) void convt3_cls_kernel(
    const u16* __restrict__ in, const float* __restrict__ w,
    const float* __restrict__ cb, float* __restrict__ out) {
  constexpr int IC = 16, IH = 152, IW = 16, TOH = 76;
  constexpr int AA = 38, IHT = 39, RW = 20, BG = 4;
  constexpr int CH = TOH * 25;  // 1900 f32 per channel tile
  __shared__ __align__(16) u16 in_s[IC * IHT * RW];
  __shared__ float w_s[9 * IC * 4];
  __shared__ __align__(16) float out_s[3 * CH];
  int nm = blockIdx.y;
  int oh0 = blockIdx.x * TOH;
  int ihb = oh0 >> 1;
  const u16* inb = in + (long)nm * IC * IH * IW;
  for (int e = threadIdx.x; e < IC * IHT * RW; e += 256) {
    int cw = e % RW;
    int r = (e / RW) % IHT;
    int ic = e / (RW * IHT);
    int ih = ihb + r;
    u16 v = 0;
    if (cw < IW && ih < IH) v = inb[(ic * IH + ih) * IW + cw];
    in_s[e] = v;
  }
  for (int e = threadIdx.x; e < 9 * IC * 4; e += 256) {
    int ocl = e % 4;
    int ic = (e / 4) % IC;
    int khw = e / 64;
    w_s[e] = (ocl < 3) ? w[(ic * 3 + ocl) * 9 + khw] : 0.f;
  }
  __syncthreads();
  float cb0 = cb[0], cb1 = cb[1], cb2 = cb[2];
  int wvid = threadIdx.x >> 6;
  int lane = threadIdx.x & 63;
  const short(*sch)[3] = SCH152[wvid];
#pragma unroll 1
  for (int s = 0; s < 3; ++s) {
    int c = sch[s][0];
    int i0 = sch[s][1], i1 = sch[s][2];
    int p = c >> 1, q = c & 1;
#pragma unroll 1
    for (int rem = i0 + lane; rem < i1; rem += 64) {
      int a = rem % AA;
      int bgi = rem / AA;
      int b0 = bgi * 4;
      float a0x = 0.f, a0y = 0.f, a0z = 0.f;
      float a1x = 0.f, a1y = 0.f, a1z = 0.f;
      float a2x = 0.f, a2y = 0.f, a2z = 0.f;
      float a3x = 0.f, a3y = 0.f, a3z = 0.f;
#pragma unroll 1
      for (int kh = 0; kh < 3; ++kh) {
        int th = p + 1 - kh;
        if (th & 1) continue;  // wave-uniform
        int r = a + (th >> 1);
        const u16* ib = &in_s[r * RW + b0];
        const float* wb = &w_s[(kh * 3) * IC * 4];
        if (q == 0) {
#pragma unroll 1
          for (int ic = 0; ic < IC; ++ic) {
            float4 iv = b2f4(*(const ushort4*)(ib + ic * IHT * RW));
            float4 wv1 = *(const float4*)(wb + (IC + ic) * 4);  // kw=1
            FM12(iv.x, iv.y, iv.z, iv.w, wv1);
          }
        } else {
#pragma unroll 1
          for (int ic = 0; ic < IC; ++ic) {
            float4 iv = b2f4(*(const ushort4*)(ib + ic * IHT * RW));
            float x4 = b2f(ib[ic * IHT * RW + 4]);
            float4 wv2 = *(const float4*)(wb + (2 * IC + ic) * 4);  // kw=2
            FM12(iv.x, iv.y, iv.z, iv.w, wv2);
            float4 wv0 = *(const float4*)(wb + ic * 4);  // kw=0, shifted
            FM12(iv.y, iv.z, iv.w, x4, wv0);
          }
        }
      }
      int ohl = 2 * a + p;  // local row in [0,76)
      int ow0 = 2 * b0 + q;
#define CT3_STB(B, AX, AY, AZ)                                           \
      do {                                                               \
        int ow_ = ow0 + 2 * (B);                                         \
        if (ow_ < 25) {                                                  \
          out_s[ohl * 25 + ow_] = (AX) + cb0;                            \
          out_s[CH + ohl * 25 + ow_] = (AY) + cb1;                       \
          out_s[2 * CH + ohl * 25 + ow_] = (AZ) + cb2;                   \
        }                                                                \
      } while (0)
      CT3_STB(0, a0x, a0y, a0z);
      CT3_STB(1, a1x, a1y, a1z);
      CT3_STB(2, a2x, a2y, a2z);
      CT3_STB(3, a3x, a3y, a3z);
#undef CT3_STB
    }
  }
  __syncthreads();
  // coalesced write-out with deferred tanh (rows beyond oh=300 dropped)
  int rows = 300 - oh0;
  if (rows > TOH) rows = TOH;
  int cnt = rows * 25;         // 1900 or 1800, both mult of 4
  int tot4 = (3 * cnt) >> 2;
  for (int e4 = threadIdx.x; e4 < tot4; e4 += 256) {
    int e = e4 << 2;
    int j = e / cnt;
    int r = e - j * cnt;
    float4 v = *(const float4*)(out_s + j * CH + r);
    v.x = ftanh(v.x); v.y = ftanh(v.y); v.z = ftanh(v.z); v.w = ftanh(v.w);
    *(float4*)(out + ((long)(nm * 3 + j) * 300 + oh0) * 25 + r) = v;
  }
}

// ---------------------------------------------------------------------------
// segmented scan over t
// ---------------------------------------------------------------------------
__global__ __launch_bounds__(256) void scan_kernel(
    const float* __restrict__ dec, const float* __restrict__ x0,
    const unsigned char* __restrict__ z, float* __restrict__ out) {
  int idx = blockIdx.x * 256 + threadIdx.x;
  if (idx >= 256 * 75) return;
  int v = idx % 25;
  int c = (idx / 25) % 3;
  int nm = idx / 75;
  int n = nm >> 1, m = nm & 1;
  const float* db = dec + ((long)(nm * 3 + c) * 300) * 25 + v;
  const unsigned char* zb = z + nm * 300;
  float* ob = out + (((long)(n * 3 + c) * 300) * 25 + v) * 2 + m;
  float x0v = x0[(nm * 3 + c) * 25 + v];
  float carry = 0.f;
  for (int t0 = 0; t0 < 300; t0 += 10) {
    float vals[10];
#pragma unroll
    for (int i = 0; i < 10; ++i) vals[i] = db[(t0 + i) * 25];
#pragma unroll
    for (int i = 0; i < 10; ++i) {
      int t = t0 + i;
      float d = (t == 0) ? x0v : vals[i];
      carry = zb[t] ? 0.f : (d + carry);
      ob[(long)t * 50] = carry;
    }
  }
}

// ---------------------------------------------------------------------------
extern "C" void kernel_launch(void* const* d_in, const int* in_sizes, int n_in,
                              void* d_out, int out_size, void* d_ws, size_t ws_size,
                              hipStream_t stream) {
  const float* x     = (const float*)d_in[0];
  const float* dbn_g = (const float*)d_in[1];
  const float* dbn_b = (const float*)d_in[2];
  const float* c1_w  = (const float*)d_in[3];
  const float* c1_b  = (const float*)d_in[4];
  const float* bn1_g = (const float*)d_in[5];
  const float* bn1_b = (const float*)d_in[6];
  const float* c2_w  = (const float*)d_in[7];
  const float* c2_b  = (const float*)d_in[8];
  const float* bn2_g = (const float*)d_in[9];
  const float* bn2_b = (const float*)d_in[10];
  const float* c3_w  = (const float*)d_in[11];
  const float* c3_b  = (const float*)d_in[12];
  const float* bn3_g = (const float*)d_in[13];
  const float* bn3_b = (const float*)d_in[14];
  const float* fc1_w = (const float*)d_in[15];
  const float* fc1_b = (const float*)d_in[16];
  const float* fc2_w = (const float*)d_in[17];
  const float* fc2_b = (const float*)d_in[18];
  const float* fc3_w = (const float*)d_in[19];
  const float* fc3_b = (const float*)d_in[20];
  const float* fc4_w = (const float*)d_in[21];
  const float* fc4_b = (const float*)d_in[22];
  const float* ct1_w = (const float*)d_in[23];
  const float* ct1_b = (const float*)d_in[24];
  const float* bn4_g = (const float*)d_in[25];
  const float* bn4_b = (const float*)d_in[26];
  const float* ct2_w = (const float*)d_in[27];
  const float* ct2_b = (const float*)d_in[28];
  const float* bn5_g = (const float*)d_in[29];
  const float* bn5_b = (const float*)d_in[30];
  const float* ct3_w = (const float*)d_in[31];
  const float* ct3_b = (const float*)d_in[32];
  float* out = (float*)d_out;

  // ---- workspace (liveness-overlapped arena, ~85.7 MB) ----
  char* ws = (char*)d_ws;
  unsigned char* zbuf = (unsigned char*)ws;             // 76,800
  float* x0 = (float*)(ws + 131072);
  // A (23.2 MB): dm -> wbA(fc1) -> wbA(fc4) -> ct3o
  char* slotA = ws + 262144;
  float* dm   = (float*)slotA;
  u16*   wbA  = (u16*)slotA;
  float* ct3o = (float*)slotA;
  // B (20.97 MB): c1o -> ct2o
  char* slotB = ws + 23461888;
  u16* c1o  = (u16*)slotB;
  u16* ct2o = (u16*)slotB;
  // P (25.8 MB): patch2 halves / patch3 -> partial -> ct1o
  char* slotP = ws + 44433408;
  u16*   patch   = (u16*)slotP;
  float* partial = (float*)slotP;
  u16*   ct1o    = (u16*)slotP;
  // D (8.7 MB): c2o -> f4
  char* slotD = ws + 70254592;
  u16* c2o = (u16*)slotD;
  u16* f4  = (u16*)slotD;
  // E (5 MB): c3o
  u16* c3o = (u16*)(ws + 78954496);
  // G: small buffers
  u16* wb2   = (u16*)(ws + 83968000);
  u16* wb3   = (u16*)(ws + 84230144);
  u16* f1    = (u16*)(ws + 84492288);
  u16* f2    = (u16*)(ws + 85016576);
  u16* f3    = (u16*)(ws + 85082112);
  u16* w2pad = (u16*)(ws + 85606400);
  u16* w3pad = (u16*)(ws + 85630976);

  prep_kernel<<<22500, 256, 0, stream>>>(x, dbn_g, dbn_b, dm, x0);
  zflag_kernel<<<19200, 256, 0, stream>>>(dm, zbuf);

  // conv1 (fp32 dm -> bf16 c1o NCHW)
  conv_tiled_kernel<float, 3, 16, 16, 8, 299, 25, 150, 13, 30, 5>
      <<<dim3(5, 256), 256, 0, stream>>>(dm, c1_w, c1_b, bn1_g, bn1_b, c1o);

  // dm now dead -> cast fc1 weights (permuted to NHWC k-order) into slot A
  wcast_fc1_kernel<<<38912, 256, 0, stream>>>(fc1_w, wbA);
  cast_kernel<<<128, 256, 0, stream>>>(fc2_w, wb2, 32768);
  cast_kernel<<<128, 256, 0, stream>>>(fc3_w, wb3, 32768);
  wpad_kernel<<<48, 256, 0, stream>>>(c2_w, w2pad, 32, 144, 192);
  wpad_kernel<<<80, 256, 0, stream>>>(c3_w, w3pad, 64, 288, 320);

  // conv2 = im2col + MFMA GEMM, two nm-halves (M=67200 each, K=192, N=32)
  for (int h = 0; h < 2; ++h) {
    im2col_kernel<16, 150, 13, 7, 144, 192, false><<<6300, 256, 0, stream>>>(
        c1o, patch, h * 67200, 525, 67200 * 24);
    fc_mfma_kernel<2><<<dim3(1050, 1, 1), 256, 0, stream>>>(
        patch, w2pad, c2_b, bn2_g, bn2_b, c2o + (long)h * 67200 * 32, nullptr,
        192, 32, 192, 32);
  }
  // conv3 = im2col + GEMM (M=38912, K=320, N=64), out NHWC = fc1's A order
  im2col_kernel<32, 75, 7, 4, 288, 320, true><<<6080, 256, 0, stream>>>(
      c2o, patch, 0, 152, 38912 * 40);
  fc_mfma_kernel<2><<<dim3(608, 1, 1), 256, 0, stream>>>(
      patch, w3pad, c3_b, bn3_g, bn3_b, c3o, nullptr, 320, 64, 320, 64);

  // fc1 split-K=8
  fc_mfma_kernel<0><<<dim3(4, 16, 8), 256, 0, stream>>>(
      c3o, wbA, nullptr, nullptr, nullptr, nullptr, partial, 9728, 1024, 1216, 0);
  fc_reduce_kernel<<<256, 256, 0, stream>>>(partial, fc1_b, f1, 262144, 1024, 8);
  cast_kernel<<<9728, 256, 0, stream>>>(fc4_w, wbA, 2490368);
  // fc2 split-K=16
  fc_mfma_kernel<0><<<dim3(4, 2, 16), 256, 0, stream>>>(
      f1, wb2, nullptr, nullptr, nullptr, nullptr, partial, 1024, 128, 64, 0);
  fc_reduce_kernel<<<32, 256, 0, stream>>>(partial, fc2_b, f2, 32768, 128, 16);
  // fc3 split-K=2
  fc_mfma_kernel<0><<<dim3(4, 16, 2), 256, 0, stream>>>(
      f2, wb3, nullptr, nullptr, nullptr, nullptr, partial, 128, 1024, 64, 0);
  fc_reduce_kernel<<<256, 256, 0, stream>>>(partial, fc3_b, f3, 262144, 1024, 2);
  // fc4 direct (N-order = NCHW flat, feeds ct1)
  fc_mfma_kernel<1><<<dim3(4, 152, 1), 256, 0, stream>>>(
      f3, wbA, fc4_b, nullptr, nullptr, f4, nullptr, 1024, 9728, 1024, 9728);

  // decoder: parity-class convT (bf16 LDS, rolled loops, LPT wave balance)
  convt_cls_kernel<64, 32, 16, 38, 4, 38, 2>
      <<<dim3(4, 256), 256, 0, stream>>>(f4, ct1_w, ct1_b, bn4_g, bn4_b, ct1o);
  convt_cls_kernel<32, 16, 16, 76, 8, 38, 4>
      <<<dim3(4, 256), 256, 0, stream>>>(ct1o, ct2_w, ct2_b, bn5_g, bn5_b, ct2o);
  convt3_cls_kernel<<<dim3(4, 256), 256, 0, stream>>>(ct2o, ct3_w, ct3_b, ct3o);

  scan_kernel<<<75, 256, 0, stream>>>(ct3o, x0, zbuf, out);
}

// Round 10
// 610.505 us; speedup vs baseline: 1.1133x; 1.0127x over previous
//
#include <hip/hip_runtime.h>
#include <math.h>

#define LRELU(y) ((y) > 0.f ? (y) : 0.01f * (y))
__device__ __constant__ float BNS = 0.99999500003749969f; // 1/sqrt(1+1e-5)

typedef unsigned short u16;
typedef __attribute__((ext_vector_type(8))) short bf16x8;
typedef __attribute__((ext_vector_type(4))) float f32x4;

__device__ inline u16 f2b(float f) {
  union { float f; unsigned u; } x; x.f = f;
  return (u16)((x.u + 0x7FFFu + ((x.u >> 16) & 1u)) >> 16);
}
__device__ inline float b2f(u16 b) {
  union { unsigned u; float f; } x; x.u = ((unsigned)b) << 16;
  return x.f;
}
__device__ inline float4 b2f4(ushort4 u) {
  float4 r;
  r.x = b2f(u.x); r.y = b2f(u.y); r.z = b2f(u.z); r.w = b2f(u.w);
  return r;
}
__device__ inline float ldv(const float* p) { return *p; }
__device__ inline float ldv(const u16* p) { return b2f(*p); }

// fast tanh: 1 - 2/(e^{2|x|}+1), sign restored. exp-based, no libcall.
__device__ inline float ftanh(float x) {
  float e = __expf(2.0f * fabsf(x));
  float t = 1.0f - 2.0f / (e + 1.0f);
  return x < 0.f ? -t : t;
}

// Named-scalar FMA expansions (VGPR-only accumulators).
#define FM16(I0, I1, I2, I3, WV)                                        \
  a00 += (I0) * (WV).x; a01 += (I0) * (WV).y;                           \
  a02 += (I0) * (WV).z; a03 += (I0) * (WV).w;                           \
  a10 += (I1) * (WV).x; a11 += (I1) * (WV).y;                           \
  a12 += (I1) * (WV).z; a13 += (I1) * (WV).w;                           \
  a20 += (I2) * (WV).x; a21 += (I2) * (WV).y;                           \
  a22 += (I2) * (WV).z; a23 += (I2) * (WV).w;                           \
  a30 += (I3) * (WV).x; a31 += (I3) * (WV).y;                           \
  a32 += (I3) * (WV).z; a33 += (I3) * (WV).w;

#define FM12(I0, I1, I2, I3, WV)                                        \
  a0x += (I0) * (WV).x; a0y += (I0) * (WV).y; a0z += (I0) * (WV).z;     \
  a1x += (I1) * (WV).x; a1y += (I1) * (WV).y; a1z += (I1) * (WV).z;     \
  a2x += (I2) * (WV).x; a2y += (I2) * (WV).y; a2z += (I2) * (WV).z;     \
  a3x += (I3) * (WV).x; a3y += (I3) * (WV).y; a3z += (I3) * (WV).z;

// ---------------------------------------------------------------------------
// Static LPT schedules for parity-class convT (ct2/ct3, still VALU).
// Entry = {class, i0, i1}. CLS=152: makespan 12->7.
// ---------------------------------------------------------------------------
__device__ __constant__ short SCH152[4][3][3] = {
  {{3, 0, 64}, {1, 128, 152}, {0, 0, 64}},
  {{3, 64, 128}, {2, 0, 64}, {0, 64, 128}},
  {{3, 128, 152}, {2, 64, 128}, {0, 128, 152}},
  {{1, 0, 64}, {1, 64, 128}, {2, 128, 152}},
};

// ---------------------------------------------------------------------------
// ct1 MFMA tap tables. Class c=(p<<1|q): taps (kh,kw) with th=p+1-kh even,
// tw=q+1-kw even; shifts sh=(p+1-kh)/2, sw=(q+1-kw)/2.
// TAPS[t] = {khw, sh, sw}; per-class base TAPB, K (=taps*64), elem base CB.
// ---------------------------------------------------------------------------
__device__ __constant__ short CT1_TAPS[9][3] = {
  {4, 0, 0},                              // c0: (kh1,kw1)
  {3, 0, 1}, {5, 0, 0},                   // c1: (kh1,kw0 sh.w), (kh1,kw2)
  {1, 1, 0}, {7, 0, 0},                   // c2: (kh0,kw1 sh.h), (kh2,kw1)
  {0, 1, 1}, {2, 1, 0}, {6, 0, 1}, {8, 0, 0},  // c3
};
__device__ __constant__ int CT1_TAPB[4] = {0, 1, 3, 5};
__device__ __constant__ int CT1_K[4]    = {64, 128, 128, 256};
__device__ __constant__ int CT1_CB[4]   = {0, 4096, 12288, 20480};

// ---------------------------------------------------------------------------
// cast fp32 -> bf16
// ---------------------------------------------------------------------------
__global__ __launch_bounds__(256) void cast_kernel(
    const float* __restrict__ s, u16* __restrict__ d, int n4) {
  int i = blockIdx.x * 256 + threadIdx.x;
  if (i >= n4) return;
  float4 v = ((const float4*)s)[i];
  ushort4 o;
  o.x = f2b(v.x); o.y = f2b(v.y); o.z = f2b(v.z); o.w = f2b(v.w);
  ((ushort4*)d)[i] = o;
}

// fc1 weight: cast + permute columns k=oc*152+sp -> k'=sp*64+oc
__global__ __launch_bounds__(256) void wcast_fc1_kernel(
    const float* __restrict__ w, u16* __restrict__ wp) {
  int idx = blockIdx.x * 256 + threadIdx.x;
  if (idx >= 1024 * 9728) return;
  int n = idx / 9728, kp = idx % 9728;
  int sp = kp >> 6, oc = kp & 63;
  wp[idx] = f2b(w[(long)n * 9728 + oc * 152 + sp]);
}

// conv weight -> padded bf16 (64 x KP)
__global__ __launch_bounds__(256) void wpad_kernel(
    const float* __restrict__ w, u16* __restrict__ wp, int OC, int K, int KP) {
  int idx = blockIdx.x * 256 + threadIdx.x;
  if (idx >= 64 * KP) return;
  int row = idx / KP, col = idx % KP;
  wp[idx] = (row < OC && col < K) ? f2b(w[row * K + col]) : (u16)0;
}

// ct1 weights -> per-class transposed bf16 Wt: wt[CB[c] + n*K + t*64 + ic]
// = w[(ic*32+n)*9 + khw_t] (n<32), 0 otherwise. Total 36864 u16.
__global__ __launch_bounds__(256) void wct1_kernel(
    const float* __restrict__ w, u16* __restrict__ wt) {
  int idx = blockIdx.x * 256 + threadIdx.x;
  if (idx >= 36864) return;
  int c = (idx < 4096) ? 0 : (idx < 12288) ? 1 : (idx < 20480) ? 2 : 3;
  int off = idx - CT1_CB[c];
  int K = CT1_K[c];
  int n = off / K;
  int rem = off - n * K;
  int t = rem >> 6, ic = rem & 63;
  int khw = CT1_TAPS[CT1_TAPB[c] + t][0];
  wt[idx] = (n < 32) ? f2b(w[(ic * 32 + n) * 9 + khw]) : (u16)0;
}

// ---------------------------------------------------------------------------
// prep: x (128,3,300,25,2) -> dm (256,3,299,25) fp32, x0 (256,3,25) fp32
// ---------------------------------------------------------------------------
__global__ __launch_bounds__(256) void prep_kernel(
    const float* __restrict__ x, const float* __restrict__ g,
    const float* __restrict__ b, float* __restrict__ dm,
    float* __restrict__ x0) {
  int idx = blockIdx.x * 256 + threadIdx.x;
  if (idx >= 256 * 3 * 300 * 25) return;
  int v = idx % 25;
  int t = (idx / 25) % 300;
  int c = (idx / (25 * 300)) % 3;
  int nm = idx / (25 * 300 * 3);
  int n = nm >> 1, m = nm & 1;
  int ch = m * 75 + v * 3 + c;
  float s = g[ch] * BNS, bb = b[ch];
  long xi = (((long)(n * 3 + c) * 300 + t) * 25 + v) * 2 + m;
  float xm_t = x[xi] * s + bb;
  if (t == 0) x0[(nm * 3 + c) * 25 + v] = xm_t;
  if (t < 299) {
    float xm_t1 = x[xi + 50] * s + bb;
    dm[((nm * 3 + c) * 299 + t) * 25 + v] = xm_t1 - xm_t;
  }
}

// ---------------------------------------------------------------------------
// z flags: one wave per (nm,t)
// ---------------------------------------------------------------------------
__global__ __launch_bounds__(256) void zflag_kernel(
    const float* __restrict__ dm, unsigned char* __restrict__ z) {
  int gw = blockIdx.x * 4 + (threadIdx.x >> 6);
  if (gw >= 256 * 300) return;
  int lane = threadIdx.x & 63;
  int t = gw % 300, nm = gw / 300;
  bool nz = false;
  if (t < 299) {
    const float* base = dm + (long)nm * 3 * 299 * 25 + t * 25;
    if (lane < 75) {
      int c = lane / 25, v = lane % 25;
      nz = base[c * 299 * 25 + v] != 0.f;
    }
    int l2 = lane + 64;
    if (l2 < 75) {
      int c = l2 / 25, v = l2 % 25;
      nz = nz || (base[c * 299 * 25 + v] != 0.f);
    }
  }
  unsigned long long mask = __ballot(nz);
  if (lane == 0) z[nm * 300 + t] = (unsigned char)((t < 299) && (mask == 0ull));
}

// ---------------------------------------------------------------------------
// conv1 (VALU tiled, fp32 in, bf16 out)
// ---------------------------------------------------------------------------
template <typename TI, int IC, int OC, int OCB, int ACC, int H, int W, int OH,
          int OW, int TOH, int NTILE>
__global__ __launch_bounds__(256) void conv_tiled_kernel(
    const TI* __restrict__ in, const float* __restrict__ w,
    const float* __restrict__ cb, const float* __restrict__ bg,
    const float* __restrict__ bnb, u16* __restrict__ out) {
  constexpr int IHT = 2 * TOH + 1;
  constexpr int RL = W + 2;
  __shared__ float in_s[IC * IHT * RL];
  __shared__ float w_s[9 * IC * OCB];
  int bx = blockIdx.x;
  int nm = blockIdx.y;
  int tile = bx % NTILE;
  int oc0 = (bx / NTILE) * OCB;
  int oh0 = tile * TOH;
  int ih0 = 2 * oh0 - 1;
  const TI* inb = in + (long)nm * IC * H * W;
  for (int e = threadIdx.x; e < IC * IHT * RL; e += 256) {
    int c = e % RL;
    int r = (e / RL) % IHT;
    int ic = e / (RL * IHT);
    int ih = ih0 + r, iw = c - 1;
    float v = 0.f;
    if (ih >= 0 && ih < H && iw >= 0 && iw < W) v = ldv(&inb[(ic * H + ih) * W + iw]);
    in_s[e] = v;
  }
  for (int e = threadIdx.x; e < 9 * IC * OCB; e += 256) {
    int ocl = e % OCB;
    int ic = (e / OCB) % IC;
    int khw = e / (OCB * IC);
    int kh = khw / 3, kw = khw % 3;
    w_s[e] = w[(((oc0 + ocl) * IC + ic) * 3 + kh) * 3 + kw];
  }
  __syncthreads();
  constexpr int NPOS = TOH * OW;
  constexpr int NWI = NPOS * (OCB / ACC);
  for (int wi = threadIdx.x; wi < NWI; wi += 256) {
    int pos = wi % NPOS;
    int jb = (wi / NPOS) * ACC;
    int ow = pos % OW;
    int oh_l = pos / OW;
    int oh = oh0 + oh_l;
    if (oh >= OH) continue;
    float acc[ACC];
#pragma unroll
    for (int j = 0; j < ACC; ++j) acc[j] = 0.f;
    for (int kh = 0; kh < 3; ++kh) {
      int r = 2 * oh_l + kh;
      for (int kw = 0; kw < 3; ++kw) {
        int cc = 2 * ow + kw;
        const float* ip = &in_s[r * RL + cc];
        const float* wp = &w_s[(kh * 3 + kw) * IC * OCB + jb];
        for (int ic = 0; ic < IC; ++ic) {
          float a = ip[ic * IHT * RL];
#pragma unroll
          for (int j = 0; j < ACC; ++j) acc[j] += a * wp[ic * OCB + j];
        }
      }
    }
#pragma unroll
    for (int j = 0; j < ACC; ++j) {
      int oc = oc0 + jb + j;
      float y = (acc[j] + cb[oc]) * (bg[oc] * BNS) + bnb[oc];
      out[((long)nm * OC + oc) * OH * OW + oh * OW + ow] = f2b(LRELU(y));
    }
  }
}

// ---------------------------------------------------------------------------
// im2col: build bf16 patch (m, KP), stride-2, pad 1, 3x3.
// ---------------------------------------------------------------------------
template <int IC, int H, int W, int OWW, int K, int KP, bool NHWC>
__global__ __launch_bounds__(256) void im2col_kernel(
    const u16* __restrict__ in, u16* __restrict__ patch, int m_off,
    int spatial, int n_threads) {
  int idx = blockIdx.x * 256 + threadIdx.x;
  if (idx >= n_threads) return;
  constexpr int KP8 = KP / 8;
  int m = idx / KP8;
  int k0 = (idx % KP8) * 8;
  int gm = m_off + m;
  int nm = gm / spatial, sp = gm % spatial;
  int oh = sp / OWW, ow = sp % OWW;
  __align__(16) u16 vals[8];
#pragma unroll
  for (int j = 0; j < 8; ++j) {
    int k = k0 + j;
    u16 v = 0;
    if (k < K) {
      int ic = k / 9, tap = k % 9;
      int ih = 2 * oh + tap / 3 - 1, iw = 2 * ow + tap % 3 - 1;
      if ((unsigned)ih < (unsigned)H && (unsigned)iw < (unsigned)W)
        v = NHWC ? in[((long)nm * H * W + ih * W + iw) * IC + ic]
                 : in[((long)nm * IC + ic) * H * W + ih * W + iw];
    }
    vals[j] = v;
  }
  *(uint4*)(patch + (long)m * KP + k0) = *(uint4*)vals;
}

// ---------------------------------------------------------------------------
// MFMA GEMM: out[m][n] = epilogue(sum_k A[m][k]*Wt[n][k]).
// EPI: 0=split-K fp32 partial; 1=bias+lrelu bf16; 2=conv BN+lrelu bf16
// ---------------------------------------------------------------------------
template <int EPI>
__global__ __launch_bounds__(256) void fc_mfma_kernel(
    const u16* __restrict__ A, const u16* __restrict__ Wt,
    const float* __restrict__ p0, const float* __restrict__ p1,
    const float* __restrict__ p2, u16* __restrict__ out,
    float* __restrict__ partial, int K, int N, int ksegLen, int nvalid) {
  __shared__ u16 As[64][72];
  __shared__ u16 Bs[64][72];
  int tid = threadIdx.x;
  int m0 = blockIdx.x * 64, n0 = blockIdx.y * 64;
  long kbase = (long)blockIdx.z * ksegLen;
  int row = tid >> 3;
  int seg = (tid & 7) * 8;
  const u16* ap0 = A + (long)(m0 + row) * K + kbase + seg;
  const u16* ap1 = A + (long)(m0 + row + 32) * K + kbase + seg;
  const u16* bp0 = Wt + (long)(n0 + row) * K + kbase + seg;
  const u16* bp1 = Wt + (long)(n0 + row + 32) * K + kbase + seg;
  uint4 ra0 = *(const uint4*)ap0;
  uint4 ra1 = *(const uint4*)ap1;
  uint4 rb0 = *(const uint4*)bp0;
  uint4 rb1 = *(const uint4*)bp1;
  int wv = tid >> 6, lane = tid & 63;
  int lr = lane & 15, q = lane >> 4;
  int mb = (wv >> 1) * 32, nb = (wv & 1) * 32;
  f32x4 acc[2][2] = {};
  for (int k0 = 0; k0 < ksegLen; k0 += 64) {
    *(uint4*)&As[row][seg] = ra0;
    *(uint4*)&As[row + 32][seg] = ra1;
    *(uint4*)&Bs[row][seg] = rb0;
    *(uint4*)&Bs[row + 32][seg] = rb1;
    __syncthreads();
    if (k0 + 64 < ksegLen) {
      ra0 = *(const uint4*)(ap0 + k0 + 64);
      ra1 = *(const uint4*)(ap1 + k0 + 64);
      rb0 = *(const uint4*)(bp0 + k0 + 64);
      rb1 = *(const uint4*)(bp1 + k0 + 64);
    }
#pragma unroll
    for (int kk = 0; kk < 64; kk += 32) {
      bf16x8 a0 = *(bf16x8*)&As[mb + lr][kk + q * 8];
      bf16x8 a1 = *(bf16x8*)&As[mb + 16 + lr][kk + q * 8];
      bf16x8 b0 = *(bf16x8*)&Bs[nb + lr][kk + q * 8];
      bf16x8 b1 = *(bf16x8*)&Bs[nb + 16 + lr][kk + q * 8];
      acc[0][0] = __builtin_amdgcn_mfma_f32_16x16x32_bf16(a0, b0, acc[0][0], 0, 0, 0);
      acc[0][1] = __builtin_amdgcn_mfma_f32_16x16x32_bf16(a0, b1, acc[0][1], 0, 0, 0);
      acc[1][0] = __builtin_amdgcn_mfma_f32_16x16x32_bf16(a1, b0, acc[1][0], 0, 0, 0);
      acc[1][1] = __builtin_amdgcn_mfma_f32_16x16x32_bf16(a1, b1, acc[1][1], 0, 0, 0);
    }
    __syncthreads();
  }
#pragma unroll
  for (int mi = 0; mi < 2; ++mi)
#pragma unroll
    for (int ni = 0; ni < 2; ++ni) {
      int col = n0 + nb + ni * 16 + lr;
      if (EPI == 2 && col >= nvalid) continue;
      float b0v = 0.f, scv = 1.f, shv = 0.f;
      if (EPI == 1) b0v = p0[col];
      if (EPI == 2) { b0v = p0[col]; scv = p1[col] * BNS; shv = p2[col]; }
#pragma unroll
      for (int r = 0; r < 4; ++r) {
        int grow = m0 + mb + mi * 16 + q * 4 + r;
        float y = acc[mi][ni][r];
        if (EPI == 0) {
          partial[((long)blockIdx.z * 256 + grow) * N + col] = y;
        } else if (EPI == 1) {
          out[(long)grow * N + col] = f2b(LRELU(y + b0v));
        } else {
          out[(long)grow * N + col] = f2b(LRELU((y + b0v) * scv + shv));
        }
      }
    }
}

// ---------------------------------------------------------------------------
// split-K reduce
// ---------------------------------------------------------------------------
__global__ __launch_bounds__(256) void fc_reduce_kernel(
    const float* __restrict__ partial, const float* __restrict__ bias,
    u16* __restrict__ out, int MN, int N, int S) {
  int i = blockIdx.x * 256 + threadIdx.x;
  if (i * 4 >= MN) return;
  float4 s = ((const float4*)partial)[i];
  for (int t = 1; t < S; ++t) {
    float4 p = ((const float4*)partial)[(long)t * (MN >> 2) + i];
    s.x += p.x; s.y += p.y; s.z += p.z; s.w += p.w;
  }
  int col = (i * 4) % N;
  float4 bv = *(const float4*)(bias + col);
  ushort4 o;
  o.x = f2b(LRELU(s.x + bv.x));
  o.y = f2b(LRELU(s.y + bv.y));
  o.z = f2b(LRELU(s.z + bv.z));
  o.w = f2b(LRELU(s.w + bv.w));
  ((ushort4*)out)[i] = o;
}

// ---------------------------------------------------------------------------
// ct1 via MFMA: per (class, mtile, nm) block computes a 64x64 tile (32 N
// valid) of out[m=positions][n=oc]. A-fragments read directly from an
// ic-contiguous LDS copy of the input (one tap per 64-wide K-step since
// IC=64); B staged from pre-transposed WtC like fc_mfma. Replaces the
// VALU-floor-bound convt_cls ct1 (75us, r9).
// grid: (12 = 4 classes x 3 mtiles, 256 nm)
// ---------------------------------------------------------------------------
__global__ __launch_bounds__(256) void ct1_mfma_kernel(
    const u16* __restrict__ in, const u16* __restrict__ wt,
    const float* __restrict__ cb, const float* __restrict__ bg,
    const float* __restrict__ bnb, u16* __restrict__ out) {
  constexpr int ICP = 72;
  __shared__ __align__(16) u16 in_s[153 * ICP];  // 152 spatial slots + zero row
  __shared__ __align__(16) u16 Bs[64][72];
  int cls = blockIdx.x & 3, mt = blockIdx.x >> 2;
  int nm = blockIdx.y;
  int m0 = mt * 64;
  int tid = threadIdx.x;
  const u16* inb = in + (long)nm * 9728;  // [ic=64][s=152] bf16
  for (int e = tid; e < 9800; e += 256) {
    if (e < 9728) in_s[(e % 152) * ICP + e / 152] = inb[e];
    else in_s[152 * ICP + (e - 9728)] = 0;
  }
  int K = CT1_K[cls], cbase = CT1_CB[cls], tb = CT1_TAPB[cls];
  int p = cls >> 1, qc = cls & 1;
  int row = tid >> 3, seg = (tid & 7) * 8;
  int wv = tid >> 6, lane = tid & 63;
  int lr = lane & 15, qq = lane >> 4;
  int mb = (wv >> 1) * 32, nb = (wv & 1) * 32;
  f32x4 acc[2][2] = {};
  int nstep = K >> 6;
  for (int st = 0; st < nstep; ++st) {
    __syncthreads();  // in_s ready (st=0) / prior MFMA reads of Bs done
    *(uint4*)&Bs[row][seg] =
        *(const uint4*)(wt + cbase + (long)row * K + st * 64 + seg);
    *(uint4*)&Bs[row + 32][seg] =
        *(const uint4*)(wt + cbase + (long)(row + 32) * K + st * 64 + seg);
    __syncthreads();
    int sh = CT1_TAPS[tb + st][1], sw = CT1_TAPS[tb + st][2];
    int s0, s1;
    {
      int m = m0 + mb + lr;
      int a = m >> 2, b = m & 3;
      int ih = a + sh, iw = b + sw;
      s0 = (m < 152 && ih < 38 && iw < 4) ? (ih * 4 + iw) : 152;
      m = m0 + mb + 16 + lr;
      a = m >> 2; b = m & 3; ih = a + sh; iw = b + sw;
      s1 = (m < 152 && ih < 38 && iw < 4) ? (ih * 4 + iw) : 152;
    }
#pragma unroll
    for (int kk = 0; kk < 64; kk += 32) {
      bf16x8 a0 = *(bf16x8*)&in_s[s0 * ICP + kk + qq * 8];
      bf16x8 a1 = *(bf16x8*)&in_s[s1 * ICP + kk + qq * 8];
      bf16x8 b0 = *(bf16x8*)&Bs[nb + lr][kk + qq * 8];
      bf16x8 b1 = *(bf16x8*)&Bs[nb + 16 + lr][kk + qq * 8];
      acc[0][0] = __builtin_amdgcn_mfma_f32_16x16x32_bf16(a0, b0, acc[0][0], 0, 0, 0);
      acc[0][1] = __builtin_amdgcn_mfma_f32_16x16x32_bf16(a0, b1, acc[0][1], 0, 0, 0);
      acc[1][0] = __builtin_amdgcn_mfma_f32_16x16x32_bf16(a1, b0, acc[1][0], 0, 0, 0);
      acc[1][1] = __builtin_amdgcn_mfma_f32_16x16x32_bf16(a1, b1, acc[1][1], 0, 0, 0);
    }
  }
#pragma unroll
  for (int mi = 0; mi < 2; ++mi)
#pragma unroll
    for (int ni = 0; ni < 2; ++ni) {
      int col = nb + ni * 16 + lr;
      if (col >= 32) continue;
      float c_ = cb[col], s_ = bg[col] * BNS, h_ = bnb[col];
#pragma unroll
      for (int r = 0; r < 4; ++r) {
        int m = m0 + mb + mi * 16 + qq * 4 + r;
        if (m >= 152) continue;
        int a = m >> 2, b = m & 3;
        int oh = 2 * a + p, ow = 2 * b + qc;
        float y = (acc[mi][ni][r] + c_) * s_ + h_;
        out[((long)(nm * 32 + col) * 76 + oh) * 8 + ow] = f2b(LRELU(y));
      }
    }
}

// ---------------------------------------------------------------------------
// Transposed conv via parity classes, LPT-balanced across waves (ct2 only
// now; ct1 moved to MFMA). CLS=152: makespan 12->7. bf16 LDS staging;
// rolled loops; named scalars. grid: (NTILEH * OCTOT/OCB, 256)
// ---------------------------------------------------------------------------
template <int IC, int OCTOT, int OCB, int IH, int IW, int TOH, int NTILEH>
__global__ __launch_bounds__(256) void convt_cls_kernel(
    const u16* __restrict__ in, const float* __restrict__ w,
    const float* __restrict__ cb, const float* __restrict__ bg,
    const float* __restrict__ bnb, u16* __restrict__ out) {
  constexpr int AA = TOH / 2;
  constexpr int IHT = AA + 1;
  constexpr int RW = IW + 4;
  constexpr int OH = 2 * IH, OW = 2 * IW;
  constexpr int BG = IW / 4;
  constexpr int OG = OCB / 4;
  constexpr int CLS = AA * BG * OG;
  static_assert(CLS == 152, "schedule table missing");
  constexpr int NSEG = 3;
  __shared__ __align__(16) u16 in_s[IC * IHT * RW];
  __shared__ __align__(16) u16 w_s[9 * IC * OCB];
  int nm = blockIdx.y;
  int tile = blockIdx.x % NTILEH;
  int oc0 = (blockIdx.x / NTILEH) * OCB;
  int oh0 = tile * TOH;
  int ihb = oh0 >> 1;
  const u16* inb = in + (long)nm * IC * IH * IW;
  for (int e = threadIdx.x; e < IC * IHT * RW; e += 256) {
    int cw = e % RW;
    int r = (e / RW) % IHT;
    int ic = e / (RW * IHT);
    int ih = ihb + r;
    u16 v = 0;
    if (cw < IW && ih < IH) v = inb[(ic * IH + ih) * IW + cw];
    in_s[e] = v;
  }
  for (int e = threadIdx.x; e < 9 * IC * OCB; e += 256) {
    int ocl = e % OCB;
    int ic = (e / OCB) % IC;
    int khw = e / (OCB * IC);
    w_s[e] = f2b(w[(ic * OCTOT + oc0 + ocl) * 9 + khw]);
  }
  __syncthreads();
  int wvid = threadIdx.x >> 6;
  int lane = threadIdx.x & 63;
  const short(*sch)[3] = SCH152[wvid];
#pragma unroll 1
  for (int s = 0; s < NSEG; ++s) {
    int c = sch[s][0];
    int i0 = sch[s][1], i1 = sch[s][2];
    int p = c >> 1, q = c & 1;
#pragma unroll 1
    for (int rem = i0 + lane; rem < i1; rem += 64) {
      int a = rem % AA;
      int t2 = rem / AA;
      int bgi = t2 % BG;
      int og = t2 / BG;
      int b0 = bgi * 4, oc = og * 4;
      float a00 = 0.f, a01 = 0.f, a02 = 0.f, a03 = 0.f;
      float a10 = 0.f, a11 = 0.f, a12 = 0.f, a13 = 0.f;
      float a20 = 0.f, a21 = 0.f, a22 = 0.f, a23 = 0.f;
      float a30 = 0.f, a31 = 0.f, a32 = 0.f, a33 = 0.f;
#pragma unroll 1
      for (int kh = 0; kh < 3; ++kh) {
        int th = p + 1 - kh;
        if (th & 1) continue;  // wave-uniform
        int r = a + (th >> 1);
        const u16* ib = &in_s[r * RW + b0];
        const u16* wb = &w_s[(kh * 3) * IC * OCB + oc];
        if (q == 0) {
#pragma unroll 1
          for (int ic = 0; ic < IC; ++ic) {
            float4 iv = b2f4(*(const ushort4*)(ib + ic * IHT * RW));
            float4 wv1 = b2f4(*(const ushort4*)(wb + (IC + ic) * OCB));  // kw=1
            FM16(iv.x, iv.y, iv.z, iv.w, wv1);
          }
        } else {
#pragma unroll 1
          for (int ic = 0; ic < IC; ++ic) {
            float4 iv = b2f4(*(const ushort4*)(ib + ic * IHT * RW));
            float x4 = b2f(ib[ic * IHT * RW + 4]);
            float4 wv2 = b2f4(*(const ushort4*)(wb + (2 * IC + ic) * OCB));  // kw=2
            FM16(iv.x, iv.y, iv.z, iv.w, wv2);
            float4 wv0 = b2f4(*(const ushort4*)(wb + ic * OCB));  // kw=0, shifted
            FM16(iv.y, iv.z, iv.w, x4, wv0);
          }
        }
      }
      int oh = oh0 + 2 * a + p;
      if (oh >= OH) continue;
      int ow0 = 2 * b0 + q;
#define CT_STJ(J, A0, A1, A2, A3)                                        \
      do {                                                               \
        int o_ = oc0 + oc + (J);                                         \
        float c_ = cb[o_], s_ = bg[o_] * BNS, h_ = bnb[o_];              \
        u16* op_ = out + ((long)(nm * OCTOT + o_) * OH + oh) * OW + ow0; \
        float y0_ = ((A0) + c_) * s_ + h_;                               \
        float y1_ = ((A1) + c_) * s_ + h_;                               \
        float y2_ = ((A2) + c_) * s_ + h_;                               \
        float y3_ = ((A3) + c_) * s_ + h_;                               \
        op_[0] = f2b(LRELU(y0_)); op_[2] = f2b(LRELU(y1_));              \
        op_[4] = f2b(LRELU(y2_)); op_[6] = f2b(LRELU(y3_));              \
      } while (0)
      CT_STJ(0, a00, a10, a20, a30);
      CT_STJ(1, a01, a11, a21, a31);
      CT_STJ(2, a02, a12, a22, a32);
      CT_STJ(3, a03, a13, a23, a33);
#undef CT_STJ
    }
  }
}

// ---------------------------------------------------------------------------
// ct3 parity-class, LPT-balanced (CLS=152, makespan 12->7): 16->3, tanh,
// fp32 out (256,3,300,25). bf16 in_s; fp32 w_s; named scalar accumulators;
// rolled loops; raw acc+bias staged to LDS; tanh deferred to coalesced
// float4 write-out. grid (4, 256)
// ---------------------------------------------------------------------------
__global__ __launch_bounds__(256) void convt3_cls_kernel(
    const u16* __restrict__ in, const float* __restrict__ w,
    const float* __restrict__ cb, float* __restrict__ out) {
  constexpr int IC = 16, IH = 152, IW = 16, TOH = 76;
  constexpr int AA = 38, IHT = 39, RW = 20, BG = 4;
  constexpr int CH = TOH * 25;  // 1900 f32 per channel tile
  __shared__ __align__(16) u16 in_s[IC * IHT * RW];
  __shared__ float w_s[9 * IC * 4];
  __shared__ __align__(16) float out_s[3 * CH];
  int nm = blockIdx.y;
  int oh0 = blockIdx.x * TOH;
  int ihb = oh0 >> 1;
  const u16* inb = in + (long)nm * IC * IH * IW;
  for (int e = threadIdx.x; e < IC * IHT * RW; e += 256) {
    int cw = e % RW;
    int r = (e / RW) % IHT;
    int ic = e / (RW * IHT);
    int ih = ihb + r;
    u16 v = 0;
    if (cw < IW && ih < IH) v = inb[(ic * IH + ih) * IW + cw];
    in_s[e] = v;
  }
  for (int e = threadIdx.x; e < 9 * IC * 4; e += 256) {
    int ocl = e % 4;
    int ic = (e / 4) % IC;
    int khw = e / 64;
    w_s[e] = (ocl < 3) ? w[(ic * 3 + ocl) * 9 + khw] : 0.f;
  }
  __syncthreads();
  float cb0 = cb[0], cb1 = cb[1], cb2 = cb[2];
  int wvid = threadIdx.x >> 6;
  int lane = threadIdx.x & 63;
  const short(*sch)[3] = SCH152[wvid];
#pragma unroll 1
  for (int s = 0; s < 3; ++s) {
    int c = sch[s][0];
    int i0 = sch[s][1], i1 = sch[s][2];
    int p = c >> 1, q = c & 1;
#pragma unroll 1
    for (int rem = i0 + lane; rem < i1; rem += 64) {
      int a = rem % AA;
      int bgi = rem / AA;
      int b0 = bgi * 4;
      float a0x = 0.f, a0y = 0.f, a0z = 0.f;
      float a1x = 0.f, a1y = 0.f, a1z = 0.f;
      float a2x = 0.f, a2y = 0.f, a2z = 0.f;
      float a3x = 0.f, a3y = 0.f, a3z = 0.f;
#pragma unroll 1
      for (int kh = 0; kh < 3; ++kh) {
        int th = p + 1 - kh;
        if (th & 1) continue;  // wave-uniform
        int r = a + (th >> 1);
        const u16* ib = &in_s[r * RW + b0];
        const float* wb = &w_s[(kh * 3) * IC * 4];
        if (q == 0) {
#pragma unroll 1
          for (int ic = 0; ic < IC; ++ic) {
            float4 iv = b2f4(*(const ushort4*)(ib + ic * IHT * RW));
            float4 wv1 = *(const float4*)(wb + (IC + ic) * 4);  // kw=1
            FM12(iv.x, iv.y, iv.z, iv.w, wv1);
          }
        } else {
#pragma unroll 1
          for (int ic = 0; ic < IC; ++ic) {
            float4 iv = b2f4(*(const ushort4*)(ib + ic * IHT * RW));
            float x4 = b2f(ib[ic * IHT * RW + 4]);
            float4 wv2 = *(const float4*)(wb + (2 * IC + ic) * 4);  // kw=2
            FM12(iv.x, iv.y, iv.z, iv.w, wv2);
            float4 wv0 = *(const float4*)(wb + ic * 4);  // kw=0, shifted
            FM12(iv.y, iv.z, iv.w, x4, wv0);
          }
        }
      }
      int ohl = 2 * a + p;  // local row in [0,76)
      int ow0 = 2 * b0 + q;
#define CT3_STB(B, AX, AY, AZ)                                           \
      do {                                                               \
        int ow_ = ow0 + 2 * (B);                                         \
        if (ow_ < 25) {                                                  \
          out_s[ohl * 25 + ow_] = (AX) + cb0;                            \
          out_s[CH + ohl * 25 + ow_] = (AY) + cb1;                       \
          out_s[2 * CH + ohl * 25 + ow_] = (AZ) + cb2;                   \
        }                                                                \
      } while (0)
      CT3_STB(0, a0x, a0y, a0z);
      CT3_STB(1, a1x, a1y, a1z);
      CT3_STB(2, a2x, a2y, a2z);
      CT3_STB(3, a3x, a3y, a3z);
#undef CT3_STB
    }
  }
  __syncthreads();
  // coalesced write-out with deferred tanh (rows beyond oh=300 dropped)
  int rows = 300 - oh0;
  if (rows > TOH) rows = TOH;
  int cnt = rows * 25;         // 1900 or 1800, both mult of 4
  int tot4 = (3 * cnt) >> 2;
  for (int e4 = threadIdx.x; e4 < tot4; e4 += 256) {
    int e = e4 << 2;
    int j = e / cnt;
    int r = e - j * cnt;
    float4 v = *(const float4*)(out_s + j * CH + r);
    v.x = ftanh(v.x); v.y = ftanh(v.y); v.z = ftanh(v.z); v.w = ftanh(v.w);
    *(float4*)(out + ((long)(nm * 3 + j) * 300 + oh0) * 25 + r) = v;
  }
}

// ---------------------------------------------------------------------------
// segmented scan over t
// ---------------------------------------------------------------------------
__global__ __launch_bounds__(256) void scan_kernel(
    const float* __restrict__ dec, const float* __restrict__ x0,
    const unsigned char* __restrict__ z, float* __restrict__ out) {
  int idx = blockIdx.x * 256 + threadIdx.x;
  if (idx >= 256 * 75) return;
  int v = idx % 25;
  int c = (idx / 25) % 3;
  int nm = idx / 75;
  int n = nm >> 1, m = nm & 1;
  const float* db = dec + ((long)(nm * 3 + c) * 300) * 25 + v;
  const unsigned char* zb = z + nm * 300;
  float* ob = out + (((long)(n * 3 + c) * 300) * 25 + v) * 2 + m;
  float x0v = x0[(nm * 3 + c) * 25 + v];
  float carry = 0.f;
  for (int t0 = 0; t0 < 300; t0 += 10) {
    float vals[10];
#pragma unroll
    for (int i = 0; i < 10; ++i) vals[i] = db[(t0 + i) * 25];
#pragma unroll
    for (int i = 0; i < 10; ++i) {
      int t = t0 + i;
      float d = (t == 0) ? x0v : vals[i];
      carry = zb[t] ? 0.f : (d + carry);
      ob[(long)t * 50] = carry;
    }
  }
}

// ---------------------------------------------------------------------------
extern "C" void kernel_launch(void* const* d_in, const int* in_sizes, int n_in,
                              void* d_out, int out_size, void* d_ws, size_t ws_size,
                              hipStream_t stream) {
  const float* x     = (const float*)d_in[0];
  const float* dbn_g = (const float*)d_in[1];
  const float* dbn_b = (const float*)d_in[2];
  const float* c1_w  = (const float*)d_in[3];
  const float* c1_b  = (const float*)d_in[4];
  const float* bn1_g = (const float*)d_in[5];
  const float* bn1_b = (const float*)d_in[6];
  const float* c2_w  = (const float*)d_in[7];
  const float* c2_b  = (const float*)d_in[8];
  const float* bn2_g = (const float*)d_in[9];
  const float* bn2_b = (const float*)d_in[10];
  const float* c3_w  = (const float*)d_in[11];
  const float* c3_b  = (const float*)d_in[12];
  const float* bn3_g = (const float*)d_in[13];
  const float* bn3_b = (const float*)d_in[14];
  const float* fc1_w = (const float*)d_in[15];
  const float* fc1_b = (const float*)d_in[16];
  const float* fc2_w = (const float*)d_in[17];
  const float* fc2_b = (const float*)d_in[18];
  const float* fc3_w = (const float*)d_in[19];
  const float* fc3_b = (const float*)d_in[20];
  const float* fc4_w = (const float*)d_in[21];
  const float* fc4_b = (const float*)d_in[22];
  const float* ct1_w = (const float*)d_in[23];
  const float* ct1_b = (const float*)d_in[24];
  const float* bn4_g = (const float*)d_in[25];
  const float* bn4_b = (const float*)d_in[26];
  const float* ct2_w = (const float*)d_in[27];
  const float* ct2_b = (const float*)d_in[28];
  const float* bn5_g = (const float*)d_in[29];
  const float* bn5_b = (const float*)d_in[30];
  const float* ct3_w = (const float*)d_in[31];
  const float* ct3_b = (const float*)d_in[32];
  float* out = (float*)d_out;

  // ---- workspace (liveness-overlapped arena, ~85.7 MB) ----
  char* ws = (char*)d_ws;
  unsigned char* zbuf = (unsigned char*)ws;             // 76,800
  float* x0 = (float*)(ws + 131072);
  // A (23.2 MB): dm -> { wbA(fc1/fc4) + WtC } -> ct3o
  char* slotA = ws + 262144;
  float* dm   = (float*)slotA;
  u16*   wbA  = (u16*)slotA;
  float* ct3o = (float*)slotA;
  u16*   wtc1 = (u16*)(ws + 20447232);  // 73.7KB above wbA's 19.9MB, below slotB
  // B (20.97 MB): c1o -> ct2o
  char* slotB = ws + 23461888;
  u16* c1o  = (u16*)slotB;
  u16* ct2o = (u16*)slotB;
  // P (25.8 MB): patch2 halves / patch3 -> partial -> ct1o
  char* slotP = ws + 44433408;
  u16*   patch   = (u16*)slotP;
  float* partial = (float*)slotP;
  u16*   ct1o    = (u16*)slotP;
  // D (8.7 MB): c2o -> f4
  char* slotD = ws + 70254592;
  u16* c2o = (u16*)slotD;
  u16* f4  = (u16*)slotD;
  // E (5 MB): c3o
  u16* c3o = (u16*)(ws + 78954496);
  // G: small buffers
  u16* wb2   = (u16*)(ws + 83968000);
  u16* wb3   = (u16*)(ws + 84230144);
  u16* f1    = (u16*)(ws + 84492288);
  u16* f2    = (u16*)(ws + 85016576);
  u16* f3    = (u16*)(ws + 85082112);
  u16* w2pad = (u16*)(ws + 85606400);
  u16* w3pad = (u16*)(ws + 85630976);

  prep_kernel<<<22500, 256, 0, stream>>>(x, dbn_g, dbn_b, dm, x0);
  zflag_kernel<<<19200, 256, 0, stream>>>(dm, zbuf);

  // conv1 (fp32 dm -> bf16 c1o NCHW)
  conv_tiled_kernel<float, 3, 16, 16, 8, 299, 25, 150, 13, 30, 5>
      <<<dim3(5, 256), 256, 0, stream>>>(dm, c1_w, c1_b, bn1_g, bn1_b, c1o);

  // dm now dead -> cast fc1 weights (permuted) + ct1 MFMA weights into slot A
  wcast_fc1_kernel<<<38912, 256, 0, stream>>>(fc1_w, wbA);
  wct1_kernel<<<144, 256, 0, stream>>>(ct1_w, wtc1);
  cast_kernel<<<128, 256, 0, stream>>>(fc2_w, wb2, 32768);
  cast_kernel<<<128, 256, 0, stream>>>(fc3_w, wb3, 32768);
  wpad_kernel<<<48, 256, 0, stream>>>(c2_w, w2pad, 32, 144, 192);
  wpad_kernel<<<80, 256, 0, stream>>>(c3_w, w3pad, 64, 288, 320);

  // conv2 = im2col + MFMA GEMM, two nm-halves (M=67200 each, K=192, N=32)
  for (int h = 0; h < 2; ++h) {
    im2col_kernel<16, 150, 13, 7, 144, 192, false><<<6300, 256, 0, stream>>>(
        c1o, patch, h * 67200, 525, 67200 * 24);
    fc_mfma_kernel<2><<<dim3(1050, 1, 1), 256, 0, stream>>>(
        patch, w2pad, c2_b, bn2_g, bn2_b, c2o + (long)h * 67200 * 32, nullptr,
        192, 32, 192, 32);
  }
  // conv3 = im2col + GEMM (M=38912, K=320, N=64), out NHWC = fc1's A order
  im2col_kernel<32, 75, 7, 4, 288, 320, true><<<6080, 256, 0, stream>>>(
      c2o, patch, 0, 152, 38912 * 40);
  fc_mfma_kernel<2><<<dim3(608, 1, 1), 256, 0, stream>>>(
      patch, w3pad, c3_b, bn3_g, bn3_b, c3o, nullptr, 320, 64, 320, 64);

  // fc1 split-K=8
  fc_mfma_kernel<0><<<dim3(4, 16, 8), 256, 0, stream>>>(
      c3o, wbA, nullptr, nullptr, nullptr, nullptr, partial, 9728, 1024, 1216, 0);
  fc_reduce_kernel<<<256, 256, 0, stream>>>(partial, fc1_b, f1, 262144, 1024, 8);
  cast_kernel<<<9728, 256, 0, stream>>>(fc4_w, wbA, 2490368);
  // fc2 split-K=16
  fc_mfma_kernel<0><<<dim3(4, 2, 16), 256, 0, stream>>>(
      f1, wb2, nullptr, nullptr, nullptr, nullptr, partial, 1024, 128, 64, 0);
  fc_reduce_kernel<<<32, 256, 0, stream>>>(partial, fc2_b, f2, 32768, 128, 16);
  // fc3 split-K=2
  fc_mfma_kernel<0><<<dim3(4, 16, 2), 256, 0, stream>>>(
      f2, wb3, nullptr, nullptr, nullptr, nullptr, partial, 128, 1024, 64, 0);
  fc_reduce_kernel<<<256, 256, 0, stream>>>(partial, fc3_b, f3, 262144, 1024, 2);
  // fc4 direct (N-order = NCHW flat, feeds ct1)
  fc_mfma_kernel<1><<<dim3(4, 152, 1), 256, 0, stream>>>(
      f3, wbA, fc4_b, nullptr, nullptr, f4, nullptr, 1024, 9728, 1024, 9728);

  // decoder: ct1 via MFMA; ct2/ct3 parity-class VALU (LPT-balanced)
  ct1_mfma_kernel<<<dim3(12, 256), 256, 0, stream>>>(
      f4, wtc1, ct1_b, bn4_g, bn4_b, ct1o);
  convt_cls_kernel<32, 16, 16, 76, 8, 38, 4>
      <<<dim3(4, 256), 256, 0, stream>>>(ct1o, ct2_w, ct2_b, bn5_g, bn5_b, ct2o);
  convt3_cls_kernel<<<dim3(4, 256), 256, 0, stream>>>(ct2o, ct3_w, ct3_b, ct3o);

  scan_kernel<<<75, 256, 0, stream>>>(ct3o, x0, zbuf, out);
}